// Round 6
// baseline (1136.993 us; speedup 1.0000x reference)
//
#include <hip/hip_runtime.h>
#include <math.h>

#define NN 100000
#define EE 1600000
#define CC 20
#define DD 8
#define GG 1024
#define LL 2
#define KK (2*CC+DD)   // 48
#define EPSV 1e-5f

#define SCAN_TPB 256
#define SCAN_ELEMS 4
#define NB 98                      // ceil(NN / 1024)
#define NPAD (NB * SCAN_TPB * SCAN_ELEMS)  // 100352
#define NBUCK 391                  // ceil(NN / 256)

// ---------------- CSR build ----------------
__global__ __launch_bounds__(256) void k_hist(const int* __restrict__ ei,
                                              int* __restrict__ cnt) {
    int t = blockIdx.x * 256 + threadIdx.x;
    if (t * 4 >= EE) return;
    int4 d4 = reinterpret_cast<const int4*>(ei + EE)[t];
    atomicAdd(&cnt[d4.x], 1);
    atomicAdd(&cnt[d4.y], 1);
    atomicAdd(&cnt[d4.z], 1);
    atomicAdd(&cnt[d4.w], 1);
}

__global__ __launch_bounds__(SCAN_TPB) void k_scan_a(const int* __restrict__ cnt,
                                                     int* __restrict__ offs,
                                                     int* __restrict__ bsum) {
    __shared__ int sdata[SCAN_TPB];
    int base = blockIdx.x * (SCAN_TPB * SCAN_ELEMS) + threadIdx.x * SCAN_ELEMS;
    int v[SCAN_ELEMS];
    int tot = 0;
#pragma unroll
    for (int i = 0; i < SCAN_ELEMS; ++i) {
        int idx = base + i;
        v[i] = (idx < NN) ? cnt[idx] : 0;
        tot += v[i];
    }
    sdata[threadIdx.x] = tot;
    __syncthreads();
    for (int o = 1; o < SCAN_TPB; o <<= 1) {
        int t = (threadIdx.x >= o) ? sdata[threadIdx.x - o] : 0;
        __syncthreads();
        sdata[threadIdx.x] += t;
        __syncthreads();
    }
    int run = sdata[threadIdx.x] - tot;  // exclusive prefix of this thread
#pragma unroll
    for (int i = 0; i < SCAN_ELEMS; ++i) {
        offs[base + i] = run;
        run += v[i];
    }
    if (threadIdx.x == SCAN_TPB - 1) bsum[blockIdx.x] = sdata[threadIdx.x];
}

// scan of bsum (redundant per block) + add to offs
__global__ __launch_bounds__(256) void k_scan_bc(int* __restrict__ offs,
                                                 const int* __restrict__ bsum) {
    __shared__ int sv[SCAN_TPB];
    __shared__ int se[SCAN_TPB];
    int v = (threadIdx.x < NB) ? bsum[threadIdx.x] : 0;
    sv[threadIdx.x] = v;
    __syncthreads();
    for (int o = 1; o < SCAN_TPB; o <<= 1) {
        int t = (threadIdx.x >= o) ? sv[threadIdx.x - o] : 0;
        __syncthreads();
        sv[threadIdx.x] += t;
        __syncthreads();
    }
    se[threadIdx.x] = sv[threadIdx.x] - v;   // exclusive
    __syncthreads();
    int i = blockIdx.x * 256 + threadIdx.x;  // grid = NPAD/256 exactly
    offs[i] += se[blockIdx.x >> 2];          // (i>>10) constant per block
}

// ---- two-pass payload sort ----
// pass 1: bucket by d>>8 with per-bucket atomic cursor (time-adjacent writes)
__global__ __launch_bounds__(256) void k_scat1(
    const int* __restrict__ ei, const float* __restrict__ ea,
    const int* __restrict__ offs, int* __restrict__ bcur,
    int* __restrict__ es1, int* __restrict__ ds1, float* __restrict__ eas1)
{
    int e = blockIdx.x * 256 + threadIdx.x;
    if (e >= EE) return;
    int s = ei[e];
    int d = ei[EE + e];
    int b = d >> 8;
    int pos = offs[d & ~255] + atomicAdd(&bcur[b], 1);
    es1[pos] = s;
    ds1[pos] = d;
    const float4* src = reinterpret_cast<const float4*>(ea + (size_t)e * DD);
    float4* dst = reinterpret_cast<float4*>(eas1 + (size_t)pos * DD);
    dst[0] = src[0];
    dst[1] = src[1];
}

// pass 2: one block per bucket; LDS rank -> final sorted position (L2-local window)
__global__ __launch_bounds__(256) void k_scat2(
    const int* __restrict__ es1, const int* __restrict__ ds1,
    const float* __restrict__ eas1, const int* __restrict__ offs,
    int* __restrict__ es, int* __restrict__ ds, float* __restrict__ eas)
{
    __shared__ int cnt2[256];
    int b = blockIdx.x;
    cnt2[threadIdx.x] = 0;
    __syncthreads();
    int lo = offs[b << 8];
    int hi = offs[(b + 1) << 8];
    for (int i = lo + threadIdx.x; i < hi; i += 256) {
        int d = ds1[i];
        int r = atomicAdd(&cnt2[d & 255], 1);
        int pos = offs[d] + r;
        es[pos] = es1[i];
        ds[pos] = d;
        const float4* src = reinterpret_cast<const float4*>(eas1 + (size_t)i * DD);
        float4* dst = reinterpret_cast<float4*>(eas + (size_t)pos * DD);
        dst[0] = src[0];
        dst[1] = src[1];
    }
}

// ---- fallback single-pass fill (if ws too small for temps) ----
__global__ __launch_bounds__(256) void k_fill(const int* __restrict__ ei,
                                              const float* __restrict__ ea,
                                              const int* __restrict__ offs,
                                              int* __restrict__ cur,
                                              int* __restrict__ es,
                                              int* __restrict__ ds,
                                              float* __restrict__ eas) {
    int e = blockIdx.x * 256 + threadIdx.x;
    if (e >= EE) return;
    int s = ei[e];
    int d = ei[EE + e];
    int pos = offs[d] + atomicAdd(&cur[d], 1);
    es[pos] = s;
    ds[pos] = d;
    const float4* src = reinterpret_cast<const float4*>(ea + (size_t)e * DD);
    float4* dst = reinterpret_cast<float4*>(eas + (size_t)pos * DD);
    dst[0] = src[0];
    dst[1] = src[1];
}

// ---------------- per-node precompute: P0 = [bf + x@Wf[0:20] | bs + x@Ws[0:20]]
//                  PX = [x@Wf[20:40] | x@Ws[20:40]] ; y := x (residual init)
__global__ __launch_bounds__(256) void k_pre0(
    const float* __restrict__ x,
    const float* __restrict__ wf, const float* __restrict__ bf,
    const float* __restrict__ wsm, const float* __restrict__ bs,
    float* __restrict__ P0, float* __restrict__ PX, float* __restrict__ y)
{
    int n = blockIdx.x * 256 + threadIdx.x;
    if (n >= NN) return;
    float xn[CC];
    const float4* xp = reinterpret_cast<const float4*>(x + (size_t)n * CC);
    float4* yp = reinterpret_cast<float4*>(y + (size_t)n * CC);
#pragma unroll
    for (int q = 0; q < 5; ++q) {
        float4 t = xp[q];
        yp[q] = t;
        xn[4*q+0] = t.x; xn[4*q+1] = t.y; xn[4*q+2] = t.z; xn[4*q+3] = t.w;
    }
    float f0[CC], g0[CC], fx[CC], gx[CC];
#pragma unroll
    for (int c = 0; c < CC; ++c) { f0[c] = bf[c]; g0[c] = bs[c]; fx[c] = 0.f; gx[c] = 0.f; }
#pragma unroll
    for (int k = 0; k < CC; ++k) {
        float zk = xn[k];
#pragma unroll
        for (int c = 0; c < CC; ++c) {
            f0[c] = fmaf(zk, wf[k*CC + c], f0[c]);
            g0[c] = fmaf(zk, wsm[k*CC + c], g0[c]);
            fx[c] = fmaf(zk, wf[(CC+k)*CC + c], fx[c]);
            gx[c] = fmaf(zk, wsm[(CC+k)*CC + c], gx[c]);
        }
    }
    float4* pp = reinterpret_cast<float4*>(P0 + (size_t)n * 2*CC);
    float4* px = reinterpret_cast<float4*>(PX + (size_t)n * 2*CC);
#pragma unroll
    for (int q = 0; q < 5; ++q) {
        pp[q]   = make_float4(f0[4*q+0], f0[4*q+1], f0[4*q+2], f0[4*q+3]);
        pp[5+q] = make_float4(g0[4*q+0], g0[4*q+1], g0[4*q+2], g0[4*q+3]);
        px[q]   = make_float4(fx[4*q+0], fx[4*q+1], fx[4*q+2], fx[4*q+3]);
        px[5+q] = make_float4(gx[4*q+0], gx[4*q+1], gx[4*q+2], gx[4*q+3]);
    }
}

// ---------------- BN(prev layer) + tanh in place, then precompute for next layer
__global__ __launch_bounds__(256) void k_bnpre(
    float* __restrict__ y, const float* __restrict__ sums,
    const float* __restrict__ gam, const float* __restrict__ bet,
    const float* __restrict__ wf, const float* __restrict__ bf,
    const float* __restrict__ wsm, const float* __restrict__ bs,
    float* __restrict__ P0, float* __restrict__ PX)
{
    int n = blockIdx.x * 256 + threadIdx.x;
    if (n >= NN) return;
    const float inv = 1.0f / (float)NN;
    float4* yp = reinterpret_cast<float4*>(y + (size_t)n * CC);
    float xn[CC];
#pragma unroll
    for (int q = 0; q < 5; ++q) {
        float4 t = yp[q];
        xn[4*q+0] = t.x; xn[4*q+1] = t.y; xn[4*q+2] = t.z; xn[4*q+3] = t.w;
    }
#pragma unroll
    for (int c = 0; c < CC; ++c) {
        float mean = sums[c] * inv;
        float var  = sums[CC + c] * inv - mean * mean;
        float scale = gam[c] * rsqrtf(var + EPSV);
        float shift = bet[c] - mean * scale;
        xn[c] = tanhf(fmaf(xn[c], scale, shift));
    }
#pragma unroll
    for (int q = 0; q < 5; ++q)
        yp[q] = make_float4(xn[4*q+0], xn[4*q+1], xn[4*q+2], xn[4*q+3]);

    float f0[CC], g0[CC], fx[CC], gx[CC];
#pragma unroll
    for (int c = 0; c < CC; ++c) { f0[c] = bf[c]; g0[c] = bs[c]; fx[c] = 0.f; gx[c] = 0.f; }
#pragma unroll
    for (int k = 0; k < CC; ++k) {
        float zk = xn[k];
#pragma unroll
        for (int c = 0; c < CC; ++c) {
            f0[c] = fmaf(zk, wf[k*CC + c], f0[c]);
            g0[c] = fmaf(zk, wsm[k*CC + c], g0[c]);
            fx[c] = fmaf(zk, wf[(CC+k)*CC + c], fx[c]);
            gx[c] = fmaf(zk, wsm[(CC+k)*CC + c], gx[c]);
        }
    }
    float4* pp = reinterpret_cast<float4*>(P0 + (size_t)n * 2*CC);
    float4* px = reinterpret_cast<float4*>(PX + (size_t)n * 2*CC);
#pragma unroll
    for (int q = 0; q < 5; ++q) {
        pp[q]   = make_float4(f0[4*q+0], f0[4*q+1], f0[4*q+2], f0[4*q+3]);
        pp[5+q] = make_float4(g0[4*q+0], g0[4*q+1], g0[4*q+2], g0[4*q+3]);
        px[q]   = make_float4(fx[4*q+0], fx[4*q+1], fx[4*q+2], fx[4*q+3]);
        px[5+q] = make_float4(gx[4*q+0], gx[4*q+1], gx[4*q+2], gx[4*q+3]);
    }
}

// ---------------- edge message (sorted index i) ----------------
__device__ __forceinline__ void edge_msg(int i, int s, int d,
    const float* __restrict__ eas, const float* __restrict__ P0,
    const float* __restrict__ PX,
    const float* __restrict__ wfe, const float* __restrict__ wse,
    float* m)
{
    const float4* eap = reinterpret_cast<const float4*>(eas + (size_t)i * DD);
    float4 ea0 = eap[0], ea1 = eap[1];
    float eaw[8] = {ea0.x, ea0.y, ea0.z, ea0.w, ea1.x, ea1.y, ea1.z, ea1.w};
    const float4* p0 = reinterpret_cast<const float4*>(P0 + (size_t)d * 2*CC);
    const float4* px = reinterpret_cast<const float4*>(PX + (size_t)s * 2*CC);
    float f[CC], g[CC];
#pragma unroll
    for (int q = 0; q < 5; ++q) {
        float4 a = p0[q], b = px[q];
        f[4*q+0] = a.x + b.x; f[4*q+1] = a.y + b.y;
        f[4*q+2] = a.z + b.z; f[4*q+3] = a.w + b.w;
    }
#pragma unroll
    for (int q = 0; q < 5; ++q) {
        float4 a = p0[5+q], b = px[5+q];
        g[4*q+0] = a.x + b.x; g[4*q+1] = a.y + b.y;
        g[4*q+2] = a.z + b.z; g[4*q+3] = a.w + b.w;
    }
#pragma unroll
    for (int k = 0; k < 8; ++k) {
        float zk = eaw[k];
#pragma unroll
        for (int c = 0; c < CC; ++c) {
            f[c] = fmaf(zk, wfe[k*CC + c], f[c]);
            g[c] = fmaf(zk, wse[k*CC + c], g[c]);
        }
    }
#pragma unroll
    for (int c = 0; c < CC; ++c) {
        float sg = 1.0f / (1.0f + __expf(-f[c]));
        float sp = fmaxf(g[c], 0.0f) + __logf(1.0f + __expf(-fabsf(g[c])));
        m[c] = sg * sp;
    }
}

__device__ __forceinline__ void commit(float* __restrict__ y, int d,
                                       const float* acc, bool complete) {
    float* yp = y + (size_t)d * CC;
    if (complete) {
        float4* y4 = reinterpret_cast<float4*>(yp);
#pragma unroll
        for (int q = 0; q < 5; ++q) {
            float4 t = y4[q];
            t.x += acc[4*q+0]; t.y += acc[4*q+1];
            t.z += acc[4*q+2]; t.w += acc[4*q+3];
            y4[q] = t;
        }
    } else {
#pragma unroll
        for (int c = 0; c < CC; ++c) atomicAdd(yp + c, acc[c]);
    }
}

// ---------------- fused edge kernel: 4 sorted edges/thread, wave seg-reduce ----------------
__global__ __launch_bounds__(256) void k_msg(
    const int* __restrict__ es, const int* __restrict__ ds,
    const float* __restrict__ eas, const int* __restrict__ offs,
    const float* __restrict__ P0, const float* __restrict__ PX,
    const float* __restrict__ wfe, const float* __restrict__ wse,
    float* __restrict__ y)
{
    int t = blockIdx.x * 256 + threadIdx.x;
    int i0 = t * 4;
    if (i0 >= EE) return;               // whole-wave uniform exit (EE/4 % 64 == 0)
    int lane = threadIdx.x & 63;
    int W = i0 & ~255;                  // wave's first sorted-edge index

    int4 sv4 = reinterpret_cast<const int4*>(es)[t];
    int4 dv4 = reinterpret_cast<const int4*>(ds)[t];
    int s_[4] = {sv4.x, sv4.y, sv4.z, sv4.w};
    int d_[4] = {dv4.x, dv4.y, dv4.z, dv4.w};

    float trail[CC], lead[CC], m[CC];
    int trail_d, lead_d = -1;

    edge_msg(i0, s_[0], d_[0], eas, P0, PX, wfe, wse, trail);
    trail_d = d_[0];
#pragma unroll
    for (int j = 1; j < 4; ++j) {
        edge_msg(i0 + j, s_[j], d_[j], eas, P0, PX, wfe, wse, m);
        if (d_[j] == trail_d) {
#pragma unroll
            for (int c = 0; c < CC; ++c) trail[c] += m[c];
        } else {
            if (lead_d < 0) {
#pragma unroll
                for (int c = 0; c < CC; ++c) lead[c] = trail[c];
                lead_d = trail_d;
            } else {
                commit(y, trail_d, trail, true);   // run fully inside thread
            }
#pragma unroll
            for (int c = 0; c < CC; ++c) trail[c] = m[c];
            trail_d = d_[j];
        }
    }

    // segmented inclusive scan of trail across lanes (d monotone -> simple pred)
    float mk[6];
#pragma unroll
    for (int k = 0; k < 6; ++k) {
        int off = 1 << k;
        int dfrom = __shfl_up(trail_d, off);
        mk[k] = (lane >= off && dfrom == trail_d) ? 1.0f : 0.0f;
    }
#pragma unroll
    for (int k = 0; k < 6; ++k) {
        int off = 1 << k;
#pragma unroll
        for (int c = 0; c < CC; ++c) {
            float tt = __shfl_up(trail[c], off);
            trail[c] = fmaf(tt, mk[k], trail[c]);
        }
    }
    int dt_next = __shfl_down(trail_d, 1);
    int ld_next = __shfl_down(lead_d, 1);
    int d_prev = __shfl_up(trail_d, 1);
    float gate = (lane > 0 && d_prev == lead_d) ? 1.0f : 0.0f;
#pragma unroll
    for (int c = 0; c < CC; ++c) {
        float tt = __shfl_up(trail[c], 1);
        lead[c] = fmaf(tt, gate, lead[c]);
    }

    bool tail = (lane == 63) || (dt_next != trail_d && ld_next != trail_d);
    if (tail) {
        int o0 = offs[trail_d], o1 = offs[trail_d + 1];
        bool complete = (o0 >= W) && (o1 == i0 + 4);
        commit(y, trail_d, trail, complete);
    }
    if (lead_d >= 0) {
        int o0 = offs[lead_d];
        commit(y, lead_d, lead, o0 >= W);   // run ends mid-thread -> within wave
    }
}

// ---------------- BN stats: grid-stride, block-level reduction ----------------
#define STAT_BLOCKS 128
__global__ __launch_bounds__(256) void k_bnstats(const float* __restrict__ y,
                                                 float* __restrict__ sums)
{
    __shared__ float ls[4][2 * CC];
    float s0[CC], s1[CC];
#pragma unroll
    for (int c = 0; c < CC; ++c) { s0[c] = 0.0f; s1[c] = 0.0f; }
    for (int n = blockIdx.x * 256 + threadIdx.x; n < NN; n += STAT_BLOCKS * 256) {
        const float4* p = reinterpret_cast<const float4*>(y + (size_t)n * CC);
#pragma unroll
        for (int q = 0; q < 5; ++q) {
            float4 t = p[q];
            s0[4*q+0] += t.x; s1[4*q+0] += t.x * t.x;
            s0[4*q+1] += t.y; s1[4*q+1] += t.y * t.y;
            s0[4*q+2] += t.z; s1[4*q+2] += t.z * t.z;
            s0[4*q+3] += t.w; s1[4*q+3] += t.w * t.w;
        }
    }
    int lane = threadIdx.x & 63;
    int wave = threadIdx.x >> 6;
#pragma unroll
    for (int c = 0; c < CC; ++c) {
        float a = s0[c], b = s1[c];
        for (int o = 32; o > 0; o >>= 1) {
            a += __shfl_down(a, o);
            b += __shfl_down(b, o);
        }
        if (lane == 0) { ls[wave][c] = a; ls[wave][CC + c] = b; }
    }
    __syncthreads();
    if (threadIdx.x < 2 * CC) {
        float tot = ls[0][threadIdx.x] + ls[1][threadIdx.x] +
                    ls[2][threadIdx.x] + ls[3][threadIdx.x];
        atomicAdd(&sums[threadIdx.x], tot);
    }
}

// ---------------- final: BN + tanh + global_add_pool ----------------
__global__ __launch_bounds__(256) void k_bnpool(
    const float* __restrict__ y, const float* __restrict__ sums,
    const float* __restrict__ gam, const float* __restrict__ bet,
    const int* __restrict__ batch, float* __restrict__ pooled)
{
    int n = blockIdx.x * 256 + threadIdx.x;
    int nc = n < NN ? n : NN - 1;
    bool valid = n < NN;
    int g = batch[nc];
    const float inv = 1.0f / (float)NN;
    float v[CC];
    const float4* p = reinterpret_cast<const float4*>(y + (size_t)nc * CC);
#pragma unroll
    for (int q = 0; q < 5; ++q) {
        float4 t = p[q];
        v[4*q+0] = t.x; v[4*q+1] = t.y; v[4*q+2] = t.z; v[4*q+3] = t.w;
    }
#pragma unroll
    for (int c = 0; c < CC; ++c) {
        float mean = sums[c] * inv;
        float var  = sums[CC + c] * inv - mean * mean;
        float scale = gam[c] * rsqrtf(var + EPSV);
        float shift = bet[c] - mean * scale;
        v[c] = tanhf(fmaf(v[c], scale, shift));
        if (!valid) v[c] = 0.0f;
    }
    int lane = threadIdx.x & 63;
    int g0 = __shfl(g, 0);
    if (__all(g == g0)) {
#pragma unroll
        for (int c = 0; c < CC; ++c) {
            float a = v[c];
            for (int o = 32; o > 0; o >>= 1) a += __shfl_down(a, o);
            if (lane == 0) atomicAdd(&pooled[(size_t)g0 * CC + c], a);
        }
    } else if (valid) {
#pragma unroll
        for (int c = 0; c < CC; ++c) atomicAdd(&pooled[(size_t)g * CC + c], v[c]);
    }
}

// ---------------- final MLP ----------------
__global__ __launch_bounds__(256) void k_mlp(const float* __restrict__ pooled,
    const float* __restrict__ w1, const float* __restrict__ b1,
    const float* __restrict__ w2, const float* __restrict__ b2,
    const float* __restrict__ w3, const float* __restrict__ b3,
    float* __restrict__ out)
{
    int gi = blockIdx.x * 256 + threadIdx.x;
    if (gi >= GG) return;

    float p[CC];
    const float4* pp = reinterpret_cast<const float4*>(pooled + (size_t)gi * CC);
#pragma unroll
    for (int q = 0; q < 5; ++q) {
        float4 t = pp[q];
        p[4*q+0] = t.x; p[4*q+1] = t.y; p[4*q+2] = t.z; p[4*q+3] = t.w;
    }
    float h1[32];
#pragma unroll
    for (int j = 0; j < 32; ++j) h1[j] = b1[j];
#pragma unroll
    for (int c = 0; c < CC; ++c) {
        float pc = p[c];
#pragma unroll
        for (int j = 0; j < 32; ++j) h1[j] = fmaf(pc, w1[c*32 + j], h1[j]);
    }
#pragma unroll
    for (int j = 0; j < 32; ++j) h1[j] = tanhf(h1[j]);
    float h2[8];
#pragma unroll
    for (int j = 0; j < 8; ++j) h2[j] = b2[j];
#pragma unroll
    for (int c = 0; c < 32; ++c) {
        float hc = h1[c];
#pragma unroll
        for (int j = 0; j < 8; ++j) h2[j] = fmaf(hc, w2[c*8 + j], h2[j]);
    }
    float o = b3[0];
#pragma unroll
    for (int j = 0; j < 8; ++j) o = fmaf(tanhf(h2[j]), w3[j], o);
    out[gi] = o;
}

extern "C" void kernel_launch(void* const* d_in, const int* in_sizes, int n_in,
                              void* d_out, int out_size, void* d_ws, size_t ws_size,
                              hipStream_t stream) {
    const float* x   = (const float*)d_in[0];
    const int*   ei  = (const int*)d_in[1];
    const float* ea  = (const float*)d_in[2];
    const int*   bat = (const int*)d_in[3];
    const float* lfw = (const float*)d_in[4];
    const float* lfb = (const float*)d_in[5];
    const float* lsw = (const float*)d_in[6];
    const float* lsb = (const float*)d_in[7];
    const float* bng = (const float*)d_in[8];
    const float* bnb = (const float*)d_in[9];
    const float* w1  = (const float*)d_in[10];
    const float* b1  = (const float*)d_in[11];
    const float* w2  = (const float*)d_in[12];
    const float* b2  = (const float*)d_in[13];
    const float* w3  = (const float*)d_in[14];
    const float* b3  = (const float*)d_in[15];
    float* out = (float*)d_out;

    char* ws = (char*)d_ws;
    float* y      = (float*)ws;                        // NN*20 f
    float* P0     = y + (size_t)NN * CC;               // NN*40 f
    float* PX     = P0 + (size_t)NN * 2 * CC;          // NN*40 f
    float* eas    = PX + (size_t)NN * 2 * CC;          // EE*8 f
    int*   es     = (int*)(eas + (size_t)EE * DD);     // EE
    int*   ds     = es + EE;                           // EE
    int*   offs   = ds + EE;                           // NPAD
    int*   bsum   = offs + NPAD;                       // 256
    // zeroed region starts here:
    int*   bcur   = bsum + 256;                        // 512 (NBUCK used)
    int*   cnt    = bcur + 512;                        // NN
    int*   cur    = cnt + NN;                          // NN (fallback only)
    float* sums   = (float*)(cur + NN);                // 2*2*CC
    float* pooled = sums + 2 * 2 * CC;                 // GG*CC
    // temps for two-pass sort (beyond fallback footprint):
    float* eas1   = pooled + (size_t)GG * CC;          // EE*8 f
    int*   es1    = (int*)(eas1 + (size_t)EE * DD);    // EE
    int*   ds1    = es1 + EE;                          // EE

    size_t needed_big = (size_t)((char*)(ds1 + EE) - ws);
    bool big = ws_size >= needed_big;

    size_t zbytes = ((size_t)512 + NN + NN + 2*2*CC + (size_t)GG*CC) * sizeof(int);
    hipMemsetAsync(bcur, 0, zbytes, stream);

    // ---- CSR build + payload sort (reused by both layers) ----
    k_hist<<<(EE/4 + 255) / 256, 256, 0, stream>>>(ei, cnt);
    k_scan_a<<<NB, SCAN_TPB, 0, stream>>>(cnt, offs, bsum);
    k_scan_bc<<<NPAD / 256, 256, 0, stream>>>(offs, bsum);
    if (big) {
        k_scat1<<<(EE + 255) / 256, 256, 0, stream>>>(ei, ea, offs, bcur, es1, ds1, eas1);
        k_scat2<<<NBUCK, 256, 0, stream>>>(es1, ds1, eas1, offs, es, ds, eas);
    } else {
        k_fill<<<(EE + 255) / 256, 256, 0, stream>>>(ei, ea, offs, cur, es, ds, eas);
    }

    const int nblocks = (NN + 255) / 256;
    const int mblocks = (EE / 4 + 255) / 256;   // 1563

    // layer 0
    k_pre0<<<nblocks, 256, 0, stream>>>(x, lfw, lfb, lsw, lsb, P0, PX, y);
    k_msg<<<mblocks, 256, 0, stream>>>(es, ds, eas, offs, P0, PX,
                                       lfw + 2*CC*CC, lsw + 2*CC*CC, y);
    k_bnstats<<<STAT_BLOCKS, 256, 0, stream>>>(y, sums);
    // BN(l0)+tanh in place, precompute for layer 1
    k_bnpre<<<nblocks, 256, 0, stream>>>(y, sums, bng, bnb,
        lfw + (size_t)KK*CC, lfb + CC, lsw + (size_t)KK*CC, lsb + CC, P0, PX);
    // layer 1
    k_msg<<<mblocks, 256, 0, stream>>>(es, ds, eas, offs, P0, PX,
        lfw + (size_t)KK*CC + 2*CC*CC, lsw + (size_t)KK*CC + 2*CC*CC, y);
    k_bnstats<<<STAT_BLOCKS, 256, 0, stream>>>(y, sums + 2*CC);
    // BN(l1)+tanh+pool
    k_bnpool<<<nblocks, 256, 0, stream>>>(y, sums + 2*CC, bng + CC, bnb + CC,
                                          bat, pooled);
    k_mlp<<<(GG + 255) / 256, 256, 0, stream>>>(pooled, w1, b1, w2, b2, w3, b3, out);
}

// Round 7
// 727.998 us; speedup vs baseline: 1.5618x; 1.5618x over previous
//
#include <hip/hip_runtime.h>
#include <math.h>

#define NN 100000
#define EE 1600000
#define CC 20
#define DD 8
#define GG 1024
#define LL 2
#define KK (2*CC+DD)   // 48
#define EPSV 1e-5f

#define SCAN_TPB 256
#define SCAN_ELEMS 4
#define NB 98                      // ceil(NN / 1024)
#define NPAD (NB * SCAN_TPB * SCAN_ELEMS)  // 100352
#define RSTRIDE 16                 // record = 16 floats = 64 B (one L2 line)

// ---------------- CSR build ----------------
__global__ __launch_bounds__(256) void k_hist(const int* __restrict__ ei,
                                              int* __restrict__ cnt) {
    int t = blockIdx.x * 256 + threadIdx.x;
    if (t * 4 >= EE) return;
    int4 d4 = reinterpret_cast<const int4*>(ei + EE)[t];
    atomicAdd(&cnt[d4.x], 1);
    atomicAdd(&cnt[d4.y], 1);
    atomicAdd(&cnt[d4.z], 1);
    atomicAdd(&cnt[d4.w], 1);
}

__global__ __launch_bounds__(SCAN_TPB) void k_scan_a(const int* __restrict__ cnt,
                                                     int* __restrict__ offs,
                                                     int* __restrict__ bsum) {
    __shared__ int sdata[SCAN_TPB];
    int base = blockIdx.x * (SCAN_TPB * SCAN_ELEMS) + threadIdx.x * SCAN_ELEMS;
    int v[SCAN_ELEMS];
    int tot = 0;
#pragma unroll
    for (int i = 0; i < SCAN_ELEMS; ++i) {
        int idx = base + i;
        v[i] = (idx < NN) ? cnt[idx] : 0;
        tot += v[i];
    }
    sdata[threadIdx.x] = tot;
    __syncthreads();
    for (int o = 1; o < SCAN_TPB; o <<= 1) {
        int t = (threadIdx.x >= o) ? sdata[threadIdx.x - o] : 0;
        __syncthreads();
        sdata[threadIdx.x] += t;
        __syncthreads();
    }
    int run = sdata[threadIdx.x] - tot;  // exclusive prefix of this thread
#pragma unroll
    for (int i = 0; i < SCAN_ELEMS; ++i) {
        offs[base + i] = run;
        run += v[i];
    }
    if (threadIdx.x == SCAN_TPB - 1) bsum[blockIdx.x] = sdata[threadIdx.x];
}

// scan of bsum (redundant per block) + add to offs
__global__ __launch_bounds__(256) void k_scan_bc(int* __restrict__ offs,
                                                 const int* __restrict__ bsum) {
    __shared__ int sv[SCAN_TPB];
    __shared__ int se[SCAN_TPB];
    int v = (threadIdx.x < NB) ? bsum[threadIdx.x] : 0;
    sv[threadIdx.x] = v;
    __syncthreads();
    for (int o = 1; o < SCAN_TPB; o <<= 1) {
        int t = (threadIdx.x >= o) ? sv[threadIdx.x - o] : 0;
        __syncthreads();
        sv[threadIdx.x] += t;
        __syncthreads();
    }
    se[threadIdx.x] = sv[threadIdx.x] - v;   // exclusive
    __syncthreads();
    int i = blockIdx.x * 256 + threadIdx.x;  // grid = NPAD/256 exactly
    offs[i] += se[blockIdx.x >> 2];          // (i>>10) constant per block
}

// ---- fill: one full 64-B record per edge -> no partial-line evictions ----
__global__ __launch_bounds__(256) void k_rec(const int* __restrict__ ei,
                                             const float* __restrict__ ea,
                                             const int* __restrict__ offs,
                                             int* __restrict__ cur,
                                             float* __restrict__ rec) {
    int e = blockIdx.x * 256 + threadIdx.x;
    if (e >= EE) return;
    int s = ei[e];
    int d = ei[EE + e];
    int pos = offs[d] + atomicAdd(&cur[d], 1);
    const float4* src = reinterpret_cast<const float4*>(ea + (size_t)e * DD);
    float4 a = src[0], b = src[1];
    float4* dst = reinterpret_cast<float4*>(rec + (size_t)pos * RSTRIDE);
    dst[0] = make_float4(__int_as_float(s), __int_as_float(d), a.x, a.y);
    dst[1] = make_float4(a.z, a.w, b.x, b.y);
    dst[2] = make_float4(b.z, b.w, 0.0f, 0.0f);
    dst[3] = make_float4(0.0f, 0.0f, 0.0f, 0.0f);   // complete the 64-B line
}

// ---------------- per-node precompute: P0 = [bf + x@Wf[0:20] | bs + x@Ws[0:20]]
//                  y := x (residual init)
__global__ __launch_bounds__(256) void k_pre0(
    const float* __restrict__ x,
    const float* __restrict__ wf, const float* __restrict__ bf,
    const float* __restrict__ wsm, const float* __restrict__ bs,
    float* __restrict__ P0, float* __restrict__ y)
{
    int n = blockIdx.x * 256 + threadIdx.x;
    if (n >= NN) return;
    float xn[CC];
    const float4* xp = reinterpret_cast<const float4*>(x + (size_t)n * CC);
    float4* yp = reinterpret_cast<float4*>(y + (size_t)n * CC);
#pragma unroll
    for (int q = 0; q < 5; ++q) {
        float4 t = xp[q];
        yp[q] = t;
        xn[4*q+0] = t.x; xn[4*q+1] = t.y; xn[4*q+2] = t.z; xn[4*q+3] = t.w;
    }
    float f0[CC], g0[CC];
#pragma unroll
    for (int c = 0; c < CC; ++c) { f0[c] = bf[c]; g0[c] = bs[c]; }
#pragma unroll
    for (int k = 0; k < CC; ++k) {
        float zk = xn[k];
#pragma unroll
        for (int c = 0; c < CC; ++c) {
            f0[c] = fmaf(zk, wf[k*CC + c], f0[c]);
            g0[c] = fmaf(zk, wsm[k*CC + c], g0[c]);
        }
    }
    float4* pp = reinterpret_cast<float4*>(P0 + (size_t)n * 2*CC);
#pragma unroll
    for (int q = 0; q < 5; ++q) {
        pp[q]   = make_float4(f0[4*q+0], f0[4*q+1], f0[4*q+2], f0[4*q+3]);
        pp[5+q] = make_float4(g0[4*q+0], g0[4*q+1], g0[4*q+2], g0[4*q+3]);
    }
}

// ---------------- BN(prev layer) + tanh -> y (in place) AND xbuf snapshot,
//                  then P0 for next layer
__global__ __launch_bounds__(256) void k_bnpre(
    float* __restrict__ y, const float* __restrict__ sums,
    const float* __restrict__ gam, const float* __restrict__ bet,
    const float* __restrict__ wf, const float* __restrict__ bf,
    const float* __restrict__ wsm, const float* __restrict__ bs,
    float* __restrict__ P0, float* __restrict__ xbuf)
{
    int n = blockIdx.x * 256 + threadIdx.x;
    if (n >= NN) return;
    const float inv = 1.0f / (float)NN;
    float4* yp = reinterpret_cast<float4*>(y + (size_t)n * CC);
    float4* xo = reinterpret_cast<float4*>(xbuf + (size_t)n * CC);
    float xn[CC];
#pragma unroll
    for (int q = 0; q < 5; ++q) {
        float4 t = yp[q];
        xn[4*q+0] = t.x; xn[4*q+1] = t.y; xn[4*q+2] = t.z; xn[4*q+3] = t.w;
    }
#pragma unroll
    for (int c = 0; c < CC; ++c) {
        float mean = sums[c] * inv;
        float var  = sums[CC + c] * inv - mean * mean;
        float scale = gam[c] * rsqrtf(var + EPSV);
        float shift = bet[c] - mean * scale;
        xn[c] = tanhf(fmaf(xn[c], scale, shift));
    }
#pragma unroll
    for (int q = 0; q < 5; ++q) {
        float4 t = make_float4(xn[4*q+0], xn[4*q+1], xn[4*q+2], xn[4*q+3]);
        yp[q] = t;
        xo[q] = t;
    }

    float f0[CC], g0[CC];
#pragma unroll
    for (int c = 0; c < CC; ++c) { f0[c] = bf[c]; g0[c] = bs[c]; }
#pragma unroll
    for (int k = 0; k < CC; ++k) {
        float zk = xn[k];
#pragma unroll
        for (int c = 0; c < CC; ++c) {
            f0[c] = fmaf(zk, wf[k*CC + c], f0[c]);
            g0[c] = fmaf(zk, wsm[k*CC + c], g0[c]);
        }
    }
    float4* pp = reinterpret_cast<float4*>(P0 + (size_t)n * 2*CC);
#pragma unroll
    for (int q = 0; q < 5; ++q) {
        pp[q]   = make_float4(f0[4*q+0], f0[4*q+1], f0[4*q+2], f0[4*q+3]);
        pp[5+q] = make_float4(g0[4*q+0], g0[4*q+1], g0[4*q+2], g0[4*q+3]);
    }
}

// ---------------- edge message from record + x gather ----------------
__device__ __forceinline__ void edge_msg(int i, int& d_out,
    const float* __restrict__ rec, const float* __restrict__ xsrc,
    const float* __restrict__ P0,
    const float* __restrict__ wf, const float* __restrict__ wsm,
    float* m)
{
    const float4* rp = reinterpret_cast<const float4*>(rec + (size_t)i * RSTRIDE);
    float4 r0 = rp[0], r1 = rp[1], r2 = rp[2];
    int s = __float_as_int(r0.x);
    int d = __float_as_int(r0.y);
    d_out = d;
    float eaw[8] = {r0.z, r0.w, r1.x, r1.y, r1.z, r1.w, r2.x, r2.y};

    const float4* p0 = reinterpret_cast<const float4*>(P0 + (size_t)d * 2*CC);
    const float4* xp = reinterpret_cast<const float4*>(xsrc + (size_t)s * CC);
    float f[CC], g[CC], xs[CC];
#pragma unroll
    for (int q = 0; q < 5; ++q) {
        float4 a = p0[q];
        f[4*q+0] = a.x; f[4*q+1] = a.y; f[4*q+2] = a.z; f[4*q+3] = a.w;
        float4 b = p0[5+q];
        g[4*q+0] = b.x; g[4*q+1] = b.y; g[4*q+2] = b.z; g[4*q+3] = b.w;
        float4 xv = xp[q];
        xs[4*q+0] = xv.x; xs[4*q+1] = xv.y; xs[4*q+2] = xv.z; xs[4*q+3] = xv.w;
    }
    // x_j part: weight rows CC..2CC-1
#pragma unroll
    for (int k = 0; k < CC; ++k) {
        float zk = xs[k];
#pragma unroll
        for (int c = 0; c < CC; ++c) {
            f[c] = fmaf(zk, wf[(CC+k)*CC + c], f[c]);
            g[c] = fmaf(zk, wsm[(CC+k)*CC + c], g[c]);
        }
    }
    // edge-attr part: weight rows 2CC..KK-1
#pragma unroll
    for (int k = 0; k < 8; ++k) {
        float zk = eaw[k];
#pragma unroll
        for (int c = 0; c < CC; ++c) {
            f[c] = fmaf(zk, wf[(2*CC+k)*CC + c], f[c]);
            g[c] = fmaf(zk, wsm[(2*CC+k)*CC + c], g[c]);
        }
    }
#pragma unroll
    for (int c = 0; c < CC; ++c) {
        float sg = 1.0f / (1.0f + __expf(-f[c]));
        float sp = fmaxf(g[c], 0.0f) + __logf(1.0f + __expf(-fabsf(g[c])));
        m[c] = sg * sp;
    }
}

__device__ __forceinline__ void commit(float* __restrict__ y, int d,
                                       const float* acc, bool complete) {
    float* yp = y + (size_t)d * CC;
    if (complete) {
        float4* y4 = reinterpret_cast<float4*>(yp);
#pragma unroll
        for (int q = 0; q < 5; ++q) {
            float4 t = y4[q];
            t.x += acc[4*q+0]; t.y += acc[4*q+1];
            t.z += acc[4*q+2]; t.w += acc[4*q+3];
            y4[q] = t;
        }
    } else {
#pragma unroll
        for (int c = 0; c < CC; ++c) atomicAdd(yp + c, acc[c]);
    }
}

// ---------------- fused edge kernel: 4 sorted edges/thread, wave seg-reduce ----------------
__global__ __launch_bounds__(256) void k_msg(
    const float* __restrict__ rec, const int* __restrict__ offs,
    const float* __restrict__ xsrc, const float* __restrict__ P0,
    const float* __restrict__ wf, const float* __restrict__ wsm,
    float* __restrict__ y)
{
    int t = blockIdx.x * 256 + threadIdx.x;
    int i0 = t * 4;
    if (i0 >= EE) return;               // whole-wave uniform exit (EE/4 % 64 == 0)
    int lane = threadIdx.x & 63;
    int W = i0 & ~255;                  // wave's first sorted-edge index

    float trail[CC], lead[CC], m[CC];
    int trail_d, lead_d = -1;

    edge_msg(i0, trail_d, rec, xsrc, P0, wf, wsm, trail);
#pragma unroll
    for (int j = 1; j < 4; ++j) {
        int dj;
        edge_msg(i0 + j, dj, rec, xsrc, P0, wf, wsm, m);
        if (dj == trail_d) {
#pragma unroll
            for (int c = 0; c < CC; ++c) trail[c] += m[c];
        } else {
            if (lead_d < 0) {
#pragma unroll
                for (int c = 0; c < CC; ++c) lead[c] = trail[c];
                lead_d = trail_d;
            } else {
                commit(y, trail_d, trail, true);   // run fully inside thread
            }
#pragma unroll
            for (int c = 0; c < CC; ++c) trail[c] = m[c];
            trail_d = dj;
        }
    }

    // segmented inclusive scan of trail across lanes (d monotone -> simple pred)
    float mk[6];
#pragma unroll
    for (int k = 0; k < 6; ++k) {
        int off = 1 << k;
        int dfrom = __shfl_up(trail_d, off);
        mk[k] = (lane >= off && dfrom == trail_d) ? 1.0f : 0.0f;
    }
#pragma unroll
    for (int k = 0; k < 6; ++k) {
        int off = 1 << k;
#pragma unroll
        for (int c = 0; c < CC; ++c) {
            float tt = __shfl_up(trail[c], off);
            trail[c] = fmaf(tt, mk[k], trail[c]);
        }
    }
    int dt_next = __shfl_down(trail_d, 1);
    int ld_next = __shfl_down(lead_d, 1);
    int d_prev = __shfl_up(trail_d, 1);
    float gate = (lane > 0 && d_prev == lead_d) ? 1.0f : 0.0f;
#pragma unroll
    for (int c = 0; c < CC; ++c) {
        float tt = __shfl_up(trail[c], 1);
        lead[c] = fmaf(tt, gate, lead[c]);
    }

    bool tail = (lane == 63) || (dt_next != trail_d && ld_next != trail_d);
    if (tail) {
        int o0 = offs[trail_d], o1 = offs[trail_d + 1];
        bool complete = (o0 >= W) && (o1 == i0 + 4);
        commit(y, trail_d, trail, complete);
    }
    if (lead_d >= 0) {
        int o0 = offs[lead_d];
        commit(y, lead_d, lead, o0 >= W);   // run ends mid-thread -> within wave
    }
}

// ---------------- BN stats: grid-stride, block-level reduction ----------------
#define STAT_BLOCKS 128
__global__ __launch_bounds__(256) void k_bnstats(const float* __restrict__ y,
                                                 float* __restrict__ sums)
{
    __shared__ float ls[4][2 * CC];
    float s0[CC], s1[CC];
#pragma unroll
    for (int c = 0; c < CC; ++c) { s0[c] = 0.0f; s1[c] = 0.0f; }
    for (int n = blockIdx.x * 256 + threadIdx.x; n < NN; n += STAT_BLOCKS * 256) {
        const float4* p = reinterpret_cast<const float4*>(y + (size_t)n * CC);
#pragma unroll
        for (int q = 0; q < 5; ++q) {
            float4 t = p[q];
            s0[4*q+0] += t.x; s1[4*q+0] += t.x * t.x;
            s0[4*q+1] += t.y; s1[4*q+1] += t.y * t.y;
            s0[4*q+2] += t.z; s1[4*q+2] += t.z * t.z;
            s0[4*q+3] += t.w; s1[4*q+3] += t.w * t.w;
        }
    }
    int lane = threadIdx.x & 63;
    int wave = threadIdx.x >> 6;
#pragma unroll
    for (int c = 0; c < CC; ++c) {
        float a = s0[c], b = s1[c];
        for (int o = 32; o > 0; o >>= 1) {
            a += __shfl_down(a, o);
            b += __shfl_down(b, o);
        }
        if (lane == 0) { ls[wave][c] = a; ls[wave][CC + c] = b; }
    }
    __syncthreads();
    if (threadIdx.x < 2 * CC) {
        float tot = ls[0][threadIdx.x] + ls[1][threadIdx.x] +
                    ls[2][threadIdx.x] + ls[3][threadIdx.x];
        atomicAdd(&sums[threadIdx.x], tot);
    }
}

// ---------------- final: BN + tanh + global_add_pool ----------------
__global__ __launch_bounds__(256) void k_bnpool(
    const float* __restrict__ y, const float* __restrict__ sums,
    const float* __restrict__ gam, const float* __restrict__ bet,
    const int* __restrict__ batch, float* __restrict__ pooled)
{
    int n = blockIdx.x * 256 + threadIdx.x;
    int nc = n < NN ? n : NN - 1;
    bool valid = n < NN;
    int g = batch[nc];
    const float inv = 1.0f / (float)NN;
    float v[CC];
    const float4* p = reinterpret_cast<const float4*>(y + (size_t)nc * CC);
#pragma unroll
    for (int q = 0; q < 5; ++q) {
        float4 t = p[q];
        v[4*q+0] = t.x; v[4*q+1] = t.y; v[4*q+2] = t.z; v[4*q+3] = t.w;
    }
#pragma unroll
    for (int c = 0; c < CC; ++c) {
        float mean = sums[c] * inv;
        float var  = sums[CC + c] * inv - mean * mean;
        float scale = gam[c] * rsqrtf(var + EPSV);
        float shift = bet[c] - mean * scale;
        v[c] = tanhf(fmaf(v[c], scale, shift));
        if (!valid) v[c] = 0.0f;
    }
    int lane = threadIdx.x & 63;
    int g0 = __shfl(g, 0);
    if (__all(g == g0)) {
#pragma unroll
        for (int c = 0; c < CC; ++c) {
            float a = v[c];
            for (int o = 32; o > 0; o >>= 1) a += __shfl_down(a, o);
            if (lane == 0) atomicAdd(&pooled[(size_t)g0 * CC + c], a);
        }
    } else if (valid) {
#pragma unroll
        for (int c = 0; c < CC; ++c) atomicAdd(&pooled[(size_t)g * CC + c], v[c]);
    }
}

// ---------------- final MLP ----------------
__global__ __launch_bounds__(256) void k_mlp(const float* __restrict__ pooled,
    const float* __restrict__ w1, const float* __restrict__ b1,
    const float* __restrict__ w2, const float* __restrict__ b2,
    const float* __restrict__ w3, const float* __restrict__ b3,
    float* __restrict__ out)
{
    int gi = blockIdx.x * 256 + threadIdx.x;
    if (gi >= GG) return;

    float p[CC];
    const float4* pp = reinterpret_cast<const float4*>(pooled + (size_t)gi * CC);
#pragma unroll
    for (int q = 0; q < 5; ++q) {
        float4 t = pp[q];
        p[4*q+0] = t.x; p[4*q+1] = t.y; p[4*q+2] = t.z; p[4*q+3] = t.w;
    }
    float h1[32];
#pragma unroll
    for (int j = 0; j < 32; ++j) h1[j] = b1[j];
#pragma unroll
    for (int c = 0; c < CC; ++c) {
        float pc = p[c];
#pragma unroll
        for (int j = 0; j < 32; ++j) h1[j] = fmaf(pc, w1[c*32 + j], h1[j]);
    }
#pragma unroll
    for (int j = 0; j < 32; ++j) h1[j] = tanhf(h1[j]);
    float h2[8];
#pragma unroll
    for (int j = 0; j < 8; ++j) h2[j] = b2[j];
#pragma unroll
    for (int c = 0; c < 32; ++c) {
        float hc = h1[c];
#pragma unroll
        for (int j = 0; j < 8; ++j) h2[j] = fmaf(hc, w2[c*8 + j], h2[j]);
    }
    float o = b3[0];
#pragma unroll
    for (int j = 0; j < 8; ++j) o = fmaf(tanhf(h2[j]), w3[j], o);
    out[gi] = o;
}

extern "C" void kernel_launch(void* const* d_in, const int* in_sizes, int n_in,
                              void* d_out, int out_size, void* d_ws, size_t ws_size,
                              hipStream_t stream) {
    const float* x   = (const float*)d_in[0];
    const int*   ei  = (const int*)d_in[1];
    const float* ea  = (const float*)d_in[2];
    const int*   bat = (const int*)d_in[3];
    const float* lfw = (const float*)d_in[4];
    const float* lfb = (const float*)d_in[5];
    const float* lsw = (const float*)d_in[6];
    const float* lsb = (const float*)d_in[7];
    const float* bng = (const float*)d_in[8];
    const float* bnb = (const float*)d_in[9];
    const float* w1  = (const float*)d_in[10];
    const float* b1  = (const float*)d_in[11];
    const float* w2  = (const float*)d_in[12];
    const float* b2  = (const float*)d_in[13];
    const float* w3  = (const float*)d_in[14];
    const float* b3  = (const float*)d_in[15];
    float* out = (float*)d_out;

    char* ws = (char*)d_ws;
    float* y      = (float*)ws;                        // NN*CC f      (8 MB)
    float* xbuf   = y + (size_t)NN * CC;               // NN*CC f      (8 MB)
    float* P0     = xbuf + (size_t)NN * CC;            // NN*2CC f     (16 MB)
    float* rec    = P0 + (size_t)NN * 2 * CC;          // EE*16 f      (102.4 MB)
    int*   offs   = (int*)(rec + (size_t)EE * RSTRIDE);// NPAD
    int*   bsum   = offs + NPAD;                       // 256
    // zeroed region starts here:
    int*   cnt    = bsum + 256;                        // NN
    int*   cur    = cnt + NN;                          // NN
    float* sums   = (float*)(cur + NN);                // 2 layers * 2*CC
    float* pooled = sums + 2 * 2 * CC;                 // GG*CC

    size_t zbytes = ((size_t)NN + NN + 2*2*CC + (size_t)GG*CC) * sizeof(int);
    hipMemsetAsync(cnt, 0, zbytes, stream);

    // ---- CSR build + record scatter (reused by both layers) ----
    k_hist<<<(EE/4 + 255) / 256, 256, 0, stream>>>(ei, cnt);
    k_scan_a<<<NB, SCAN_TPB, 0, stream>>>(cnt, offs, bsum);
    k_scan_bc<<<NPAD / 256, 256, 0, stream>>>(offs, bsum);
    k_rec<<<(EE + 255) / 256, 256, 0, stream>>>(ei, ea, offs, cur, rec);

    const int nblocks = (NN + 255) / 256;
    const int mblocks = (EE / 4 + 255) / 256;   // 1563

    // layer 0
    k_pre0<<<nblocks, 256, 0, stream>>>(x, lfw, lfb, lsw, lsb, P0, y);
    k_msg<<<mblocks, 256, 0, stream>>>(rec, offs, x, P0, lfw, lsw, y);
    k_bnstats<<<STAT_BLOCKS, 256, 0, stream>>>(y, sums);
    // BN(l0)+tanh -> y & xbuf, precompute P0 for layer 1
    k_bnpre<<<nblocks, 256, 0, stream>>>(y, sums, bng, bnb,
        lfw + (size_t)KK*CC, lfb + CC, lsw + (size_t)KK*CC, lsb + CC, P0, xbuf);
    // layer 1 (gather from xbuf snapshot, accumulate into y)
    k_msg<<<mblocks, 256, 0, stream>>>(rec, offs, xbuf, P0,
        lfw + (size_t)KK*CC, lsw + (size_t)KK*CC, y);
    k_bnstats<<<STAT_BLOCKS, 256, 0, stream>>>(y, sums + 2*CC);
    // BN(l1)+tanh+pool
    k_bnpool<<<nblocks, 256, 0, stream>>>(y, sums + 2*CC, bng + CC, bnb + CC,
                                          bat, pooled);
    k_mlp<<<(GG + 255) / 256, 256, 0, stream>>>(pooled, w1, b1, w2, b2, w3, b3, out);
}

// Round 8
// 643.497 us; speedup vs baseline: 1.7669x; 1.1313x over previous
//
#include <hip/hip_runtime.h>
#include <math.h>

#define NN 100000
#define EE 1600000
#define CC 20
#define DD 8
#define GG 1024
#define LL 2
#define KK (2*CC+DD)   // 48
#define EPSV 1e-5f

#define SCAN_TPB 256
#define SCAN_ELEMS 4
#define NB 98                      // ceil(NN / 1024)
#define NPAD (NB * SCAN_TPB * SCAN_ELEMS)  // 100352
#define RSTRIDE 16                 // record = 16 floats = 64 B (one L2 line)

// ---------------- CSR build ----------------
__global__ __launch_bounds__(256) void k_hist(const int* __restrict__ ei,
                                              int* __restrict__ cnt) {
    int t = blockIdx.x * 256 + threadIdx.x;
    if (t * 4 >= EE) return;
    int4 d4 = reinterpret_cast<const int4*>(ei + EE)[t];
    atomicAdd(&cnt[d4.x], 1);
    atomicAdd(&cnt[d4.y], 1);
    atomicAdd(&cnt[d4.z], 1);
    atomicAdd(&cnt[d4.w], 1);
}

__global__ __launch_bounds__(SCAN_TPB) void k_scan_a(const int* __restrict__ cnt,
                                                     int* __restrict__ offs,
                                                     int* __restrict__ bsum) {
    __shared__ int sdata[SCAN_TPB];
    int base = blockIdx.x * (SCAN_TPB * SCAN_ELEMS) + threadIdx.x * SCAN_ELEMS;
    int v[SCAN_ELEMS];
    int tot = 0;
#pragma unroll
    for (int i = 0; i < SCAN_ELEMS; ++i) {
        int idx = base + i;
        v[i] = (idx < NN) ? cnt[idx] : 0;
        tot += v[i];
    }
    sdata[threadIdx.x] = tot;
    __syncthreads();
    for (int o = 1; o < SCAN_TPB; o <<= 1) {
        int t = (threadIdx.x >= o) ? sdata[threadIdx.x - o] : 0;
        __syncthreads();
        sdata[threadIdx.x] += t;
        __syncthreads();
    }
    int run = sdata[threadIdx.x] - tot;  // exclusive prefix of this thread
#pragma unroll
    for (int i = 0; i < SCAN_ELEMS; ++i) {
        offs[base + i] = run;
        run += v[i];
    }
    if (threadIdx.x == SCAN_TPB - 1) bsum[blockIdx.x] = sdata[threadIdx.x];
}

// scan of bsum (redundant per block) + add to offs; also emit cursor copy
__global__ __launch_bounds__(256) void k_scan_bc(int* __restrict__ offs,
                                                 const int* __restrict__ bsum,
                                                 int* __restrict__ cur2) {
    __shared__ int sv[SCAN_TPB];
    __shared__ int se[SCAN_TPB];
    int v = (threadIdx.x < NB) ? bsum[threadIdx.x] : 0;
    sv[threadIdx.x] = v;
    __syncthreads();
    for (int o = 1; o < SCAN_TPB; o <<= 1) {
        int t = (threadIdx.x >= o) ? sv[threadIdx.x - o] : 0;
        __syncthreads();
        sv[threadIdx.x] += t;
        __syncthreads();
    }
    se[threadIdx.x] = sv[threadIdx.x] - v;   // exclusive
    __syncthreads();
    int i = blockIdx.x * 256 + threadIdx.x;  // grid = NPAD/256 exactly
    int o = offs[i] + se[blockIdx.x >> 2];   // (i>>10) constant per block
    offs[i] = o;
    cur2[i] = o;                             // running cursor for k_rec
}

// ---- fill: one full 64-B record per edge -> no partial-line evictions ----
__global__ __launch_bounds__(256) void k_rec(const int* __restrict__ ei,
                                             const float* __restrict__ ea,
                                             int* __restrict__ cur2,
                                             float* __restrict__ rec) {
    int e = blockIdx.x * 256 + threadIdx.x;
    if (e >= EE) return;
    int s = ei[e];
    int d = ei[EE + e];
    int pos = atomicAdd(&cur2[d], 1);        // cur2 pre-initialized to offs
    const float4* src = reinterpret_cast<const float4*>(ea + (size_t)e * DD);
    float4 a = src[0], b = src[1];
    float4* dst = reinterpret_cast<float4*>(rec + (size_t)pos * RSTRIDE);
    dst[0] = make_float4(__int_as_float(s), __int_as_float(d), a.x, a.y);
    dst[1] = make_float4(a.z, a.w, b.x, b.y);
    dst[2] = make_float4(b.z, b.w, 0.0f, 0.0f);
    dst[3] = make_float4(0.0f, 0.0f, 0.0f, 0.0f);   // complete the 64-B line
}

// ---------------- per-node precompute:
// P0 = [bf + x@Wf[0:20] | bs + x@Ws[0:20]], PX = [x@Wf[20:40] | x@Ws[20:40]]
// y := x (residual init)
__global__ __launch_bounds__(256) void k_pre0(
    const float* __restrict__ x,
    const float* __restrict__ wf, const float* __restrict__ bf,
    const float* __restrict__ wsm, const float* __restrict__ bs,
    float* __restrict__ P0, float* __restrict__ PX, float* __restrict__ y)
{
    int n = blockIdx.x * 256 + threadIdx.x;
    if (n >= NN) return;
    float xn[CC];
    const float4* xp = reinterpret_cast<const float4*>(x + (size_t)n * CC);
    float4* yp = reinterpret_cast<float4*>(y + (size_t)n * CC);
#pragma unroll
    for (int q = 0; q < 5; ++q) {
        float4 t = xp[q];
        yp[q] = t;
        xn[4*q+0] = t.x; xn[4*q+1] = t.y; xn[4*q+2] = t.z; xn[4*q+3] = t.w;
    }
    float f0[CC], g0[CC], fx[CC], gx[CC];
#pragma unroll
    for (int c = 0; c < CC; ++c) { f0[c] = bf[c]; g0[c] = bs[c]; fx[c] = 0.f; gx[c] = 0.f; }
#pragma unroll
    for (int k = 0; k < CC; ++k) {
        float zk = xn[k];
#pragma unroll
        for (int c = 0; c < CC; ++c) {
            f0[c] = fmaf(zk, wf[k*CC + c], f0[c]);
            g0[c] = fmaf(zk, wsm[k*CC + c], g0[c]);
            fx[c] = fmaf(zk, wf[(CC+k)*CC + c], fx[c]);
            gx[c] = fmaf(zk, wsm[(CC+k)*CC + c], gx[c]);
        }
    }
    float4* pp = reinterpret_cast<float4*>(P0 + (size_t)n * 2*CC);
    float4* px = reinterpret_cast<float4*>(PX + (size_t)n * 2*CC);
#pragma unroll
    for (int q = 0; q < 5; ++q) {
        pp[q]   = make_float4(f0[4*q+0], f0[4*q+1], f0[4*q+2], f0[4*q+3]);
        pp[5+q] = make_float4(g0[4*q+0], g0[4*q+1], g0[4*q+2], g0[4*q+3]);
        px[q]   = make_float4(fx[4*q+0], fx[4*q+1], fx[4*q+2], fx[4*q+3]);
        px[5+q] = make_float4(gx[4*q+0], gx[4*q+1], gx[4*q+2], gx[4*q+3]);
    }
}

// ---------------- BN(prev layer) + tanh in place, then P0/PX for next layer
__global__ __launch_bounds__(256) void k_bnpre(
    float* __restrict__ y, const float* __restrict__ sums,
    const float* __restrict__ gam, const float* __restrict__ bet,
    const float* __restrict__ wf, const float* __restrict__ bf,
    const float* __restrict__ wsm, const float* __restrict__ bs,
    float* __restrict__ P0, float* __restrict__ PX)
{
    int n = blockIdx.x * 256 + threadIdx.x;
    if (n >= NN) return;
    const float inv = 1.0f / (float)NN;
    float4* yp = reinterpret_cast<float4*>(y + (size_t)n * CC);
    float xn[CC];
#pragma unroll
    for (int q = 0; q < 5; ++q) {
        float4 t = yp[q];
        xn[4*q+0] = t.x; xn[4*q+1] = t.y; xn[4*q+2] = t.z; xn[4*q+3] = t.w;
    }
#pragma unroll
    for (int c = 0; c < CC; ++c) {
        float mean = sums[c] * inv;
        float var  = sums[CC + c] * inv - mean * mean;
        float scale = gam[c] * rsqrtf(var + EPSV);
        float shift = bet[c] - mean * scale;
        xn[c] = tanhf(fmaf(xn[c], scale, shift));
    }
#pragma unroll
    for (int q = 0; q < 5; ++q)
        yp[q] = make_float4(xn[4*q+0], xn[4*q+1], xn[4*q+2], xn[4*q+3]);

    float f0[CC], g0[CC], fx[CC], gx[CC];
#pragma unroll
    for (int c = 0; c < CC; ++c) { f0[c] = bf[c]; g0[c] = bs[c]; fx[c] = 0.f; gx[c] = 0.f; }
#pragma unroll
    for (int k = 0; k < CC; ++k) {
        float zk = xn[k];
#pragma unroll
        for (int c = 0; c < CC; ++c) {
            f0[c] = fmaf(zk, wf[k*CC + c], f0[c]);
            g0[c] = fmaf(zk, wsm[k*CC + c], g0[c]);
            fx[c] = fmaf(zk, wf[(CC+k)*CC + c], fx[c]);
            gx[c] = fmaf(zk, wsm[(CC+k)*CC + c], gx[c]);
        }
    }
    float4* pp = reinterpret_cast<float4*>(P0 + (size_t)n * 2*CC);
    float4* px = reinterpret_cast<float4*>(PX + (size_t)n * 2*CC);
#pragma unroll
    for (int q = 0; q < 5; ++q) {
        pp[q]   = make_float4(f0[4*q+0], f0[4*q+1], f0[4*q+2], f0[4*q+3]);
        pp[5+q] = make_float4(g0[4*q+0], g0[4*q+1], g0[4*q+2], g0[4*q+3]);
        px[q]   = make_float4(fx[4*q+0], fx[4*q+1], fx[4*q+2], fx[4*q+3]);
        px[5+q] = make_float4(gx[4*q+0], gx[4*q+1], gx[4*q+2], gx[4*q+3]);
    }
}

// ---------------- edge message from record + P0/PX gathers ----------------
__device__ __forceinline__ void edge_msg(int i, int& d_out,
    const float* __restrict__ rec, const float* __restrict__ P0,
    const float* __restrict__ PX,
    const float* __restrict__ wfe, const float* __restrict__ wse,
    float* m)
{
    const float4* rp = reinterpret_cast<const float4*>(rec + (size_t)i * RSTRIDE);
    float4 r0 = rp[0], r1 = rp[1], r2 = rp[2];
    int s = __float_as_int(r0.x);
    int d = __float_as_int(r0.y);
    d_out = d;
    float eaw[8] = {r0.z, r0.w, r1.x, r1.y, r1.z, r1.w, r2.x, r2.y};

    const float4* p0 = reinterpret_cast<const float4*>(P0 + (size_t)d * 2*CC);
    const float4* px = reinterpret_cast<const float4*>(PX + (size_t)s * 2*CC);
    float f[CC], g[CC];
#pragma unroll
    for (int q = 0; q < 5; ++q) {
        float4 a = p0[q], b = px[q];
        f[4*q+0] = a.x + b.x; f[4*q+1] = a.y + b.y;
        f[4*q+2] = a.z + b.z; f[4*q+3] = a.w + b.w;
    }
#pragma unroll
    for (int q = 0; q < 5; ++q) {
        float4 a = p0[5+q], b = px[5+q];
        g[4*q+0] = a.x + b.x; g[4*q+1] = a.y + b.y;
        g[4*q+2] = a.z + b.z; g[4*q+3] = a.w + b.w;
    }
    // edge-attr part: weight rows 2CC..KK-1 (wfe/wse point at row 2CC)
#pragma unroll
    for (int k = 0; k < 8; ++k) {
        float zk = eaw[k];
#pragma unroll
        for (int c = 0; c < CC; ++c) {
            f[c] = fmaf(zk, wfe[k*CC + c], f[c]);
            g[c] = fmaf(zk, wse[k*CC + c], g[c]);
        }
    }
#pragma unroll
    for (int c = 0; c < CC; ++c) {
        float sg = 1.0f / (1.0f + __expf(-f[c]));
        float sp = fmaxf(g[c], 0.0f) + __logf(1.0f + __expf(-fabsf(g[c])));
        m[c] = sg * sp;
    }
}

__device__ __forceinline__ void commit(float* __restrict__ y, int d,
                                       const float* acc, bool complete) {
    float* yp = y + (size_t)d * CC;
    if (complete) {
        float4* y4 = reinterpret_cast<float4*>(yp);
#pragma unroll
        for (int q = 0; q < 5; ++q) {
            float4 t = y4[q];
            t.x += acc[4*q+0]; t.y += acc[4*q+1];
            t.z += acc[4*q+2]; t.w += acc[4*q+3];
            y4[q] = t;
        }
    } else {
#pragma unroll
        for (int c = 0; c < CC; ++c) atomicAdd(yp + c, acc[c]);
    }
}

// ---------------- fused edge kernel: 4 sorted edges/thread, wave seg-reduce ----------------
__global__ __launch_bounds__(256) void k_msg(
    const float* __restrict__ rec, const int* __restrict__ offs,
    const float* __restrict__ P0, const float* __restrict__ PX,
    const float* __restrict__ wfe, const float* __restrict__ wse,
    float* __restrict__ y)
{
    int t = blockIdx.x * 256 + threadIdx.x;
    int i0 = t * 4;
    if (i0 >= EE) return;               // whole-wave uniform exit (EE/4 % 64 == 0)
    int lane = threadIdx.x & 63;
    int W = i0 & ~255;                  // wave's first sorted-edge index

    float trail[CC], lead[CC], m[CC];
    int trail_d, lead_d = -1;

    edge_msg(i0, trail_d, rec, P0, PX, wfe, wse, trail);
#pragma unroll
    for (int j = 1; j < 4; ++j) {
        int dj;
        edge_msg(i0 + j, dj, rec, P0, PX, wfe, wse, m);
        if (dj == trail_d) {
#pragma unroll
            for (int c = 0; c < CC; ++c) trail[c] += m[c];
        } else {
            if (lead_d < 0) {
#pragma unroll
                for (int c = 0; c < CC; ++c) lead[c] = trail[c];
                lead_d = trail_d;
            } else {
                commit(y, trail_d, trail, true);   // run fully inside thread
            }
#pragma unroll
            for (int c = 0; c < CC; ++c) trail[c] = m[c];
            trail_d = dj;
        }
    }

    // segmented inclusive scan of trail across lanes (d monotone -> simple pred)
    float mk[6];
#pragma unroll
    for (int k = 0; k < 6; ++k) {
        int off = 1 << k;
        int dfrom = __shfl_up(trail_d, off);
        mk[k] = (lane >= off && dfrom == trail_d) ? 1.0f : 0.0f;
    }
#pragma unroll
    for (int k = 0; k < 6; ++k) {
        int off = 1 << k;
#pragma unroll
        for (int c = 0; c < CC; ++c) {
            float tt = __shfl_up(trail[c], off);
            trail[c] = fmaf(tt, mk[k], trail[c]);
        }
    }
    int dt_next = __shfl_down(trail_d, 1);
    int ld_next = __shfl_down(lead_d, 1);
    int d_prev = __shfl_up(trail_d, 1);
    float gate = (lane > 0 && d_prev == lead_d) ? 1.0f : 0.0f;
#pragma unroll
    for (int c = 0; c < CC; ++c) {
        float tt = __shfl_up(trail[c], 1);
        lead[c] = fmaf(tt, gate, lead[c]);
    }

    bool tail = (lane == 63) || (dt_next != trail_d && ld_next != trail_d);
    if (tail) {
        int o0 = offs[trail_d], o1 = offs[trail_d + 1];
        bool complete = (o0 >= W) && (o1 == i0 + 4);
        commit(y, trail_d, trail, complete);
    }
    if (lead_d >= 0) {
        int o0 = offs[lead_d];
        commit(y, lead_d, lead, o0 >= W);   // run ends mid-thread -> within wave
    }
}

// ---------------- BN stats: grid-stride, block-level reduction ----------------
#define STAT_BLOCKS 128
__global__ __launch_bounds__(256) void k_bnstats(const float* __restrict__ y,
                                                 float* __restrict__ sums)
{
    __shared__ float ls[4][2 * CC];
    float s0[CC], s1[CC];
#pragma unroll
    for (int c = 0; c < CC; ++c) { s0[c] = 0.0f; s1[c] = 0.0f; }
    for (int n = blockIdx.x * 256 + threadIdx.x; n < NN; n += STAT_BLOCKS * 256) {
        const float4* p = reinterpret_cast<const float4*>(y + (size_t)n * CC);
#pragma unroll
        for (int q = 0; q < 5; ++q) {
            float4 t = p[q];
            s0[4*q+0] += t.x; s1[4*q+0] += t.x * t.x;
            s0[4*q+1] += t.y; s1[4*q+1] += t.y * t.y;
            s0[4*q+2] += t.z; s1[4*q+2] += t.z * t.z;
            s0[4*q+3] += t.w; s1[4*q+3] += t.w * t.w;
        }
    }
    int lane = threadIdx.x & 63;
    int wave = threadIdx.x >> 6;
#pragma unroll
    for (int c = 0; c < CC; ++c) {
        float a = s0[c], b = s1[c];
        for (int o = 32; o > 0; o >>= 1) {
            a += __shfl_down(a, o);
            b += __shfl_down(b, o);
        }
        if (lane == 0) { ls[wave][c] = a; ls[wave][CC + c] = b; }
    }
    __syncthreads();
    if (threadIdx.x < 2 * CC) {
        float tot = ls[0][threadIdx.x] + ls[1][threadIdx.x] +
                    ls[2][threadIdx.x] + ls[3][threadIdx.x];
        atomicAdd(&sums[threadIdx.x], tot);
    }
}

// ---------------- final: BN + tanh + global_add_pool ----------------
__global__ __launch_bounds__(256) void k_bnpool(
    const float* __restrict__ y, const float* __restrict__ sums,
    const float* __restrict__ gam, const float* __restrict__ bet,
    const int* __restrict__ batch, float* __restrict__ pooled)
{
    int n = blockIdx.x * 256 + threadIdx.x;
    int nc = n < NN ? n : NN - 1;
    bool valid = n < NN;
    int g = batch[nc];
    const float inv = 1.0f / (float)NN;
    float v[CC];
    const float4* p = reinterpret_cast<const float4*>(y + (size_t)nc * CC);
#pragma unroll
    for (int q = 0; q < 5; ++q) {
        float4 t = p[q];
        v[4*q+0] = t.x; v[4*q+1] = t.y; v[4*q+2] = t.z; v[4*q+3] = t.w;
    }
#pragma unroll
    for (int c = 0; c < CC; ++c) {
        float mean = sums[c] * inv;
        float var  = sums[CC + c] * inv - mean * mean;
        float scale = gam[c] * rsqrtf(var + EPSV);
        float shift = bet[c] - mean * scale;
        v[c] = tanhf(fmaf(v[c], scale, shift));
        if (!valid) v[c] = 0.0f;
    }
    int lane = threadIdx.x & 63;
    int g0 = __shfl(g, 0);
    if (__all(g == g0)) {
#pragma unroll
        for (int c = 0; c < CC; ++c) {
            float a = v[c];
            for (int o = 32; o > 0; o >>= 1) a += __shfl_down(a, o);
            if (lane == 0) atomicAdd(&pooled[(size_t)g0 * CC + c], a);
        }
    } else if (valid) {
#pragma unroll
        for (int c = 0; c < CC; ++c) atomicAdd(&pooled[(size_t)g * CC + c], v[c]);
    }
}

// ---------------- final MLP ----------------
__global__ __launch_bounds__(256) void k_mlp(const float* __restrict__ pooled,
    const float* __restrict__ w1, const float* __restrict__ b1,
    const float* __restrict__ w2, const float* __restrict__ b2,
    const float* __restrict__ w3, const float* __restrict__ b3,
    float* __restrict__ out)
{
    int gi = blockIdx.x * 256 + threadIdx.x;
    if (gi >= GG) return;

    float p[CC];
    const float4* pp = reinterpret_cast<const float4*>(pooled + (size_t)gi * CC);
#pragma unroll
    for (int q = 0; q < 5; ++q) {
        float4 t = pp[q];
        p[4*q+0] = t.x; p[4*q+1] = t.y; p[4*q+2] = t.z; p[4*q+3] = t.w;
    }
    float h1[32];
#pragma unroll
    for (int j = 0; j < 32; ++j) h1[j] = b1[j];
#pragma unroll
    for (int c = 0; c < CC; ++c) {
        float pc = p[c];
#pragma unroll
        for (int j = 0; j < 32; ++j) h1[j] = fmaf(pc, w1[c*32 + j], h1[j]);
    }
#pragma unroll
    for (int j = 0; j < 32; ++j) h1[j] = tanhf(h1[j]);
    float h2[8];
#pragma unroll
    for (int j = 0; j < 8; ++j) h2[j] = b2[j];
#pragma unroll
    for (int c = 0; c < 32; ++c) {
        float hc = h1[c];
#pragma unroll
        for (int j = 0; j < 8; ++j) h2[j] = fmaf(hc, w2[c*8 + j], h2[j]);
    }
    float o = b3[0];
#pragma unroll
    for (int j = 0; j < 8; ++j) o = fmaf(tanhf(h2[j]), w3[j], o);
    out[gi] = o;
}

extern "C" void kernel_launch(void* const* d_in, const int* in_sizes, int n_in,
                              void* d_out, int out_size, void* d_ws, size_t ws_size,
                              hipStream_t stream) {
    const float* x   = (const float*)d_in[0];
    const int*   ei  = (const int*)d_in[1];
    const float* ea  = (const float*)d_in[2];
    const int*   bat = (const int*)d_in[3];
    const float* lfw = (const float*)d_in[4];
    const float* lfb = (const float*)d_in[5];
    const float* lsw = (const float*)d_in[6];
    const float* lsb = (const float*)d_in[7];
    const float* bng = (const float*)d_in[8];
    const float* bnb = (const float*)d_in[9];
    const float* w1  = (const float*)d_in[10];
    const float* b1  = (const float*)d_in[11];
    const float* w2  = (const float*)d_in[12];
    const float* b2  = (const float*)d_in[13];
    const float* w3  = (const float*)d_in[14];
    const float* b3  = (const float*)d_in[15];
    float* out = (float*)d_out;

    char* ws = (char*)d_ws;
    float* y      = (float*)ws;                        // NN*CC f      (8 MB)
    float* P0     = y + (size_t)NN * CC;               // NN*2CC f     (16 MB)
    float* PX     = P0 + (size_t)NN * 2 * CC;          // NN*2CC f     (16 MB)
    float* rec    = PX + (size_t)NN * 2 * CC;          // EE*16 f      (102.4 MB)
    int*   offs   = (int*)(rec + (size_t)EE * RSTRIDE);// NPAD
    int*   cur2   = offs + NPAD;                       // NPAD (written by scan_bc)
    int*   bsum   = cur2 + NPAD;                       // 256
    // zeroed region starts here:
    int*   cnt    = bsum + 256;                        // NN
    float* sums   = (float*)(cnt + NN);                // 2 layers * 2*CC
    float* pooled = sums + 2 * 2 * CC;                 // GG*CC

    size_t zbytes = ((size_t)NN + 2*2*CC + (size_t)GG*CC) * sizeof(int);
    hipMemsetAsync(cnt, 0, zbytes, stream);

    // ---- CSR build + record scatter (reused by both layers) ----
    k_hist<<<(EE/4 + 255) / 256, 256, 0, stream>>>(ei, cnt);
    k_scan_a<<<NB, SCAN_TPB, 0, stream>>>(cnt, offs, bsum);
    k_scan_bc<<<NPAD / 256, 256, 0, stream>>>(offs, bsum, cur2);
    k_rec<<<(EE + 255) / 256, 256, 0, stream>>>(ei, ea, cur2, rec);

    const int nblocks = (NN + 255) / 256;
    const int mblocks = (EE / 4 + 255) / 256;   // 1563

    // layer 0
    k_pre0<<<nblocks, 256, 0, stream>>>(x, lfw, lfb, lsw, lsb, P0, PX, y);
    k_msg<<<mblocks, 256, 0, stream>>>(rec, offs, P0, PX,
                                       lfw + 2*CC*CC, lsw + 2*CC*CC, y);
    k_bnstats<<<STAT_BLOCKS, 256, 0, stream>>>(y, sums);
    // BN(l0)+tanh in place, precompute P0/PX for layer 1
    k_bnpre<<<nblocks, 256, 0, stream>>>(y, sums, bng, bnb,
        lfw + (size_t)KK*CC, lfb + CC, lsw + (size_t)KK*CC, lsb + CC, P0, PX);
    // layer 1
    k_msg<<<mblocks, 256, 0, stream>>>(rec, offs, P0, PX,
        lfw + (size_t)KK*CC + 2*CC*CC, lsw + (size_t)KK*CC + 2*CC*CC, y);
    k_bnstats<<<STAT_BLOCKS, 256, 0, stream>>>(y, sums + 2*CC);
    // BN(l1)+tanh+pool
    k_bnpool<<<nblocks, 256, 0, stream>>>(y, sums + 2*CC, bng + CC, bnb + CC,
                                          bat, pooled);
    k_mlp<<<(GG + 255) / 256, 256, 0, stream>>>(pooled, w1, b1, w2, b2, w3, b3, out);
}

// Round 9
// 518.127 us; speedup vs baseline: 2.1944x; 1.2420x over previous
//
#include <hip/hip_runtime.h>
#include <math.h>

#define NN 100000
#define EE 1600000
#define CC 20
#define DD 8
#define GG 1024
#define LL 2
#define KK (2*CC+DD)   // 48
#define EPSV 1e-5f

#define SCAN_TPB 256
#define SCAN_ELEMS 4
#define NB 98                      // ceil(NN / 1024)
#define NPAD (NB * SCAN_TPB * SCAN_ELEMS)  // 100352
#define RSTRIDE 16                 // record = 16 floats = 64 B (one L2 line)

// ---------------- CSR build ----------------
__global__ __launch_bounds__(256) void k_hist(const int* __restrict__ ei,
                                              int* __restrict__ cnt) {
    int t = blockIdx.x * 256 + threadIdx.x;
    if (t * 4 >= EE) return;
    int4 d4 = reinterpret_cast<const int4*>(ei + EE)[t];
    atomicAdd(&cnt[d4.x], 1);
    atomicAdd(&cnt[d4.y], 1);
    atomicAdd(&cnt[d4.z], 1);
    atomicAdd(&cnt[d4.w], 1);
}

__global__ __launch_bounds__(SCAN_TPB) void k_scan_a(const int* __restrict__ cnt,
                                                     int* __restrict__ offs,
                                                     int* __restrict__ bsum) {
    __shared__ int sdata[SCAN_TPB];
    int base = blockIdx.x * (SCAN_TPB * SCAN_ELEMS) + threadIdx.x * SCAN_ELEMS;
    int v[SCAN_ELEMS];
    int tot = 0;
#pragma unroll
    for (int i = 0; i < SCAN_ELEMS; ++i) {
        int idx = base + i;
        v[i] = (idx < NN) ? cnt[idx] : 0;
        tot += v[i];
    }
    sdata[threadIdx.x] = tot;
    __syncthreads();
    for (int o = 1; o < SCAN_TPB; o <<= 1) {
        int t = (threadIdx.x >= o) ? sdata[threadIdx.x - o] : 0;
        __syncthreads();
        sdata[threadIdx.x] += t;
        __syncthreads();
    }
    int run = sdata[threadIdx.x] - tot;  // exclusive prefix of this thread
#pragma unroll
    for (int i = 0; i < SCAN_ELEMS; ++i) {
        offs[base + i] = run;
        run += v[i];
    }
    if (threadIdx.x == SCAN_TPB - 1) bsum[blockIdx.x] = sdata[threadIdx.x];
}

// scan of bsum (redundant per block) + add to offs; also emit cursor copy
__global__ __launch_bounds__(256) void k_scan_bc(int* __restrict__ offs,
                                                 const int* __restrict__ bsum,
                                                 int* __restrict__ cur2) {
    __shared__ int sv[SCAN_TPB];
    __shared__ int se[SCAN_TPB];
    int v = (threadIdx.x < NB) ? bsum[threadIdx.x] : 0;
    sv[threadIdx.x] = v;
    __syncthreads();
    for (int o = 1; o < SCAN_TPB; o <<= 1) {
        int t = (threadIdx.x >= o) ? sv[threadIdx.x - o] : 0;
        __syncthreads();
        sv[threadIdx.x] += t;
        __syncthreads();
    }
    se[threadIdx.x] = sv[threadIdx.x] - v;   // exclusive
    __syncthreads();
    int i = blockIdx.x * 256 + threadIdx.x;  // grid = NPAD/256 exactly
    int o = offs[i] + se[blockIdx.x >> 2];   // (i>>10) constant per block
    offs[i] = o;
    cur2[i] = o;                             // running cursor for k_rec
}

// ---- fill: one full 64-B record per edge -> no partial-line evictions ----
__global__ __launch_bounds__(256) void k_rec(const int* __restrict__ ei,
                                             const float* __restrict__ ea,
                                             int* __restrict__ cur2,
                                             float* __restrict__ rec) {
    int e = blockIdx.x * 256 + threadIdx.x;
    if (e >= EE) return;
    int s = ei[e];
    int d = ei[EE + e];
    int pos = atomicAdd(&cur2[d], 1);        // cur2 pre-initialized to offs
    const float4* src = reinterpret_cast<const float4*>(ea + (size_t)e * DD);
    float4 a = src[0], b = src[1];
    float4* dst = reinterpret_cast<float4*>(rec + (size_t)pos * RSTRIDE);
    dst[0] = make_float4(__int_as_float(s), __int_as_float(d), a.x, a.y);
    dst[1] = make_float4(a.z, a.w, b.x, b.y);
    dst[2] = make_float4(b.z, b.w, 0.0f, 0.0f);
    dst[3] = make_float4(0.0f, 0.0f, 0.0f, 0.0f);   // complete the 64-B line
}

// ---------------- per-node precompute:
// P0 = [bf + x@Wf[0:20] | bs + x@Ws[0:20]], PX = [x@Wf[20:40] | x@Ws[20:40]]
// y := x (residual init)
__global__ __launch_bounds__(256) void k_pre0(
    const float* __restrict__ x,
    const float* __restrict__ wf, const float* __restrict__ bf,
    const float* __restrict__ wsm, const float* __restrict__ bs,
    float* __restrict__ P0, float* __restrict__ PX, float* __restrict__ y)
{
    int n = blockIdx.x * 256 + threadIdx.x;
    if (n >= NN) return;
    float xn[CC];
    const float4* xp = reinterpret_cast<const float4*>(x + (size_t)n * CC);
    float4* yp = reinterpret_cast<float4*>(y + (size_t)n * CC);
#pragma unroll
    for (int q = 0; q < 5; ++q) {
        float4 t = xp[q];
        yp[q] = t;
        xn[4*q+0] = t.x; xn[4*q+1] = t.y; xn[4*q+2] = t.z; xn[4*q+3] = t.w;
    }
    float f0[CC], g0[CC], fx[CC], gx[CC];
#pragma unroll
    for (int c = 0; c < CC; ++c) { f0[c] = bf[c]; g0[c] = bs[c]; fx[c] = 0.f; gx[c] = 0.f; }
#pragma unroll
    for (int k = 0; k < CC; ++k) {
        float zk = xn[k];
#pragma unroll
        for (int c = 0; c < CC; ++c) {
            f0[c] = fmaf(zk, wf[k*CC + c], f0[c]);
            g0[c] = fmaf(zk, wsm[k*CC + c], g0[c]);
            fx[c] = fmaf(zk, wf[(CC+k)*CC + c], fx[c]);
            gx[c] = fmaf(zk, wsm[(CC+k)*CC + c], gx[c]);
        }
    }
    float4* pp = reinterpret_cast<float4*>(P0 + (size_t)n * 2*CC);
    float4* px = reinterpret_cast<float4*>(PX + (size_t)n * 2*CC);
#pragma unroll
    for (int q = 0; q < 5; ++q) {
        pp[q]   = make_float4(f0[4*q+0], f0[4*q+1], f0[4*q+2], f0[4*q+3]);
        pp[5+q] = make_float4(g0[4*q+0], g0[4*q+1], g0[4*q+2], g0[4*q+3]);
        px[q]   = make_float4(fx[4*q+0], fx[4*q+1], fx[4*q+2], fx[4*q+3]);
        px[5+q] = make_float4(gx[4*q+0], gx[4*q+1], gx[4*q+2], gx[4*q+3]);
    }
}

// ---------------- BN(prev layer) + tanh in place, then P0/PX for next layer
__global__ __launch_bounds__(256) void k_bnpre(
    float* __restrict__ y, const float* __restrict__ sums,
    const float* __restrict__ gam, const float* __restrict__ bet,
    const float* __restrict__ wf, const float* __restrict__ bf,
    const float* __restrict__ wsm, const float* __restrict__ bs,
    float* __restrict__ P0, float* __restrict__ PX)
{
    int n = blockIdx.x * 256 + threadIdx.x;
    if (n >= NN) return;
    const float inv = 1.0f / (float)NN;
    float4* yp = reinterpret_cast<float4*>(y + (size_t)n * CC);
    float xn[CC];
#pragma unroll
    for (int q = 0; q < 5; ++q) {
        float4 t = yp[q];
        xn[4*q+0] = t.x; xn[4*q+1] = t.y; xn[4*q+2] = t.z; xn[4*q+3] = t.w;
    }
#pragma unroll
    for (int c = 0; c < CC; ++c) {
        float mean = sums[c] * inv;
        float var  = sums[CC + c] * inv - mean * mean;
        float scale = gam[c] * rsqrtf(var + EPSV);
        float shift = bet[c] - mean * scale;
        xn[c] = tanhf(fmaf(xn[c], scale, shift));
    }
#pragma unroll
    for (int q = 0; q < 5; ++q)
        yp[q] = make_float4(xn[4*q+0], xn[4*q+1], xn[4*q+2], xn[4*q+3]);

    float f0[CC], g0[CC], fx[CC], gx[CC];
#pragma unroll
    for (int c = 0; c < CC; ++c) { f0[c] = bf[c]; g0[c] = bs[c]; fx[c] = 0.f; gx[c] = 0.f; }
#pragma unroll
    for (int k = 0; k < CC; ++k) {
        float zk = xn[k];
#pragma unroll
        for (int c = 0; c < CC; ++c) {
            f0[c] = fmaf(zk, wf[k*CC + c], f0[c]);
            g0[c] = fmaf(zk, wsm[k*CC + c], g0[c]);
            fx[c] = fmaf(zk, wf[(CC+k)*CC + c], fx[c]);
            gx[c] = fmaf(zk, wsm[(CC+k)*CC + c], gx[c]);
        }
    }
    float4* pp = reinterpret_cast<float4*>(P0 + (size_t)n * 2*CC);
    float4* px = reinterpret_cast<float4*>(PX + (size_t)n * 2*CC);
#pragma unroll
    for (int q = 0; q < 5; ++q) {
        pp[q]   = make_float4(f0[4*q+0], f0[4*q+1], f0[4*q+2], f0[4*q+3]);
        pp[5+q] = make_float4(g0[4*q+0], g0[4*q+1], g0[4*q+2], g0[4*q+3]);
        px[q]   = make_float4(fx[4*q+0], fx[4*q+1], fx[4*q+2], fx[4*q+3]);
        px[5+q] = make_float4(gx[4*q+0], gx[4*q+1], gx[4*q+2], gx[4*q+3]);
    }
}

// ---------------- edge message from record + P0/PX gathers ----------------
__device__ __forceinline__ void edge_msg(int i, int& d_out,
    const float* __restrict__ rec, const float* __restrict__ P0,
    const float* __restrict__ PX,
    const float* __restrict__ wfe, const float* __restrict__ wse,
    float* m)
{
    const float4* rp = reinterpret_cast<const float4*>(rec + (size_t)i * RSTRIDE);
    float4 r0 = rp[0], r1 = rp[1], r2 = rp[2];
    int s = __float_as_int(r0.x);
    int d = __float_as_int(r0.y);
    d_out = d;
    float eaw[8] = {r0.z, r0.w, r1.x, r1.y, r1.z, r1.w, r2.x, r2.y};

    const float4* p0 = reinterpret_cast<const float4*>(P0 + (size_t)d * 2*CC);
    const float4* px = reinterpret_cast<const float4*>(PX + (size_t)s * 2*CC);
    float f[CC], g[CC];
#pragma unroll
    for (int q = 0; q < 5; ++q) {
        float4 a = p0[q], b = px[q];
        f[4*q+0] = a.x + b.x; f[4*q+1] = a.y + b.y;
        f[4*q+2] = a.z + b.z; f[4*q+3] = a.w + b.w;
    }
#pragma unroll
    for (int q = 0; q < 5; ++q) {
        float4 a = p0[5+q], b = px[5+q];
        g[4*q+0] = a.x + b.x; g[4*q+1] = a.y + b.y;
        g[4*q+2] = a.z + b.z; g[4*q+3] = a.w + b.w;
    }
    // edge-attr part: weight rows 2CC..KK-1 (wfe/wse point at row 2CC)
#pragma unroll
    for (int k = 0; k < 8; ++k) {
        float zk = eaw[k];
#pragma unroll
        for (int c = 0; c < CC; ++c) {
            f[c] = fmaf(zk, wfe[k*CC + c], f[c]);
            g[c] = fmaf(zk, wse[k*CC + c], g[c]);
        }
    }
#pragma unroll
    for (int c = 0; c < CC; ++c) {
        float sg = 1.0f / (1.0f + __expf(-f[c]));
        float sp = fmaxf(g[c], 0.0f) + __logf(1.0f + __expf(-fabsf(g[c])));
        m[c] = sg * sp;
    }
}

__device__ __forceinline__ void commit(float* __restrict__ y, int d,
                                       const float* acc, bool complete) {
    float* yp = y + (size_t)d * CC;
    if (complete) {
        float4* y4 = reinterpret_cast<float4*>(yp);
#pragma unroll
        for (int q = 0; q < 5; ++q) {
            float4 t = y4[q];
            t.x += acc[4*q+0]; t.y += acc[4*q+1];
            t.z += acc[4*q+2]; t.w += acc[4*q+3];
            y4[q] = t;
        }
    } else {
#pragma unroll
        for (int c = 0; c < CC; ++c) atomicAdd(yp + c, acc[c]);
    }
}

// ---------------- fused edge kernel: 4 sorted edges/thread, wave seg-reduce ----------------
__global__ __launch_bounds__(256) void k_msg(
    const float* __restrict__ rec, const int* __restrict__ offs,
    const float* __restrict__ P0, const float* __restrict__ PX,
    const float* __restrict__ wfe, const float* __restrict__ wse,
    float* __restrict__ y)
{
    int t = blockIdx.x * 256 + threadIdx.x;
    int i0 = t * 4;
    if (i0 >= EE) return;               // whole-wave uniform exit (EE/4 % 64 == 0)
    int lane = threadIdx.x & 63;
    int W = i0 & ~255;                  // wave's first sorted-edge index

    float trail[CC], lead[CC], m[CC];
    int trail_d, lead_d = -1;

    edge_msg(i0, trail_d, rec, P0, PX, wfe, wse, trail);
#pragma unroll
    for (int j = 1; j < 4; ++j) {
        int dj;
        edge_msg(i0 + j, dj, rec, P0, PX, wfe, wse, m);
        if (dj == trail_d) {
#pragma unroll
            for (int c = 0; c < CC; ++c) trail[c] += m[c];
        } else {
            if (lead_d < 0) {
#pragma unroll
                for (int c = 0; c < CC; ++c) lead[c] = trail[c];
                lead_d = trail_d;
            } else {
                commit(y, trail_d, trail, true);   // run fully inside thread
            }
#pragma unroll
            for (int c = 0; c < CC; ++c) trail[c] = m[c];
            trail_d = dj;
        }
    }

    // segmented inclusive scan of trail across lanes (d monotone -> simple pred)
    float mk[6];
#pragma unroll
    for (int k = 0; k < 6; ++k) {
        int off = 1 << k;
        int dfrom = __shfl_up(trail_d, off);
        mk[k] = (lane >= off && dfrom == trail_d) ? 1.0f : 0.0f;
    }
#pragma unroll
    for (int k = 0; k < 6; ++k) {
        int off = 1 << k;
#pragma unroll
        for (int c = 0; c < CC; ++c) {
            float tt = __shfl_up(trail[c], off);
            trail[c] = fmaf(tt, mk[k], trail[c]);
        }
    }
    int dt_next = __shfl_down(trail_d, 1);
    int ld_next = __shfl_down(lead_d, 1);
    int d_prev = __shfl_up(trail_d, 1);
    float gate = (lane > 0 && d_prev == lead_d) ? 1.0f : 0.0f;
#pragma unroll
    for (int c = 0; c < CC; ++c) {
        float tt = __shfl_up(trail[c], 1);
        lead[c] = fmaf(tt, gate, lead[c]);
    }

    bool tail = (lane == 63) || (dt_next != trail_d && ld_next != trail_d);
    if (tail) {
        int o0 = offs[trail_d], o1 = offs[trail_d + 1];
        bool complete = (o0 >= W) && (o1 == i0 + 4);
        commit(y, trail_d, trail, complete);
    }
    if (lead_d >= 0) {
        int o0 = offs[lead_d];
        commit(y, lead_d, lead, o0 >= W);   // run ends mid-thread -> within wave
    }
}

// ---------------- BN stats: grid-stride, block-level reduction ----------------
#define STAT_BLOCKS 128
__global__ __launch_bounds__(256) void k_bnstats(const float* __restrict__ y,
                                                 float* __restrict__ sums)
{
    __shared__ float ls[4][2 * CC];
    float s0[CC], s1[CC];
#pragma unroll
    for (int c = 0; c < CC; ++c) { s0[c] = 0.0f; s1[c] = 0.0f; }
    for (int n = blockIdx.x * 256 + threadIdx.x; n < NN; n += STAT_BLOCKS * 256) {
        const float4* p = reinterpret_cast<const float4*>(y + (size_t)n * CC);
#pragma unroll
        for (int q = 0; q < 5; ++q) {
            float4 t = p[q];
            s0[4*q+0] += t.x; s1[4*q+0] += t.x * t.x;
            s0[4*q+1] += t.y; s1[4*q+1] += t.y * t.y;
            s0[4*q+2] += t.z; s1[4*q+2] += t.z * t.z;
            s0[4*q+3] += t.w; s1[4*q+3] += t.w * t.w;
        }
    }
    int lane = threadIdx.x & 63;
    int wave = threadIdx.x >> 6;
#pragma unroll
    for (int c = 0; c < CC; ++c) {
        float a = s0[c], b = s1[c];
        for (int o = 32; o > 0; o >>= 1) {
            a += __shfl_down(a, o);
            b += __shfl_down(b, o);
        }
        if (lane == 0) { ls[wave][c] = a; ls[wave][CC + c] = b; }
    }
    __syncthreads();
    if (threadIdx.x < 2 * CC) {
        float tot = ls[0][threadIdx.x] + ls[1][threadIdx.x] +
                    ls[2][threadIdx.x] + ls[3][threadIdx.x];
        atomicAdd(&sums[threadIdx.x], tot);
    }
}

// ---------------- final: BN + tanh + pool via wave segmented scan ----------------
__global__ __launch_bounds__(256) void k_bnpool(
    const float* __restrict__ y, const float* __restrict__ sums,
    const float* __restrict__ gam, const float* __restrict__ bet,
    const int* __restrict__ batch, float* __restrict__ pooled)
{
    int n = blockIdx.x * 256 + threadIdx.x;
    int nc = n < NN ? n : NN - 1;
    bool valid = n < NN;
    int g = batch[nc];                 // pad lanes: g of last node, v = 0
    const float inv = 1.0f / (float)NN;
    float v[CC];
    const float4* p = reinterpret_cast<const float4*>(y + (size_t)nc * CC);
#pragma unroll
    for (int q = 0; q < 5; ++q) {
        float4 t = p[q];
        v[4*q+0] = t.x; v[4*q+1] = t.y; v[4*q+2] = t.z; v[4*q+3] = t.w;
    }
#pragma unroll
    for (int c = 0; c < CC; ++c) {
        float mean = sums[c] * inv;
        float var  = sums[CC + c] * inv - mean * mean;
        float scale = gam[c] * rsqrtf(var + EPSV);
        float shift = bet[c] - mean * scale;
        v[c] = tanhf(fmaf(v[c], scale, shift));
        if (!valid) v[c] = 0.0f;
    }
    // segmented inclusive scan across the wave keyed by g (batch sorted)
    int lane = threadIdx.x & 63;
    float mk[6];
#pragma unroll
    for (int k = 0; k < 6; ++k) {
        int off = 1 << k;
        int gfrom = __shfl_up(g, off);
        mk[k] = (lane >= off && gfrom == g) ? 1.0f : 0.0f;
    }
#pragma unroll
    for (int k = 0; k < 6; ++k) {
        int off = 1 << k;
#pragma unroll
        for (int c = 0; c < CC; ++c) {
            float tt = __shfl_up(v[c], off);
            v[c] = fmaf(tt, mk[k], v[c]);
        }
    }
    int g_next = __shfl_down(g, 1);
    bool tail = (lane == 63) || (g_next != g);
    if (tail) {
#pragma unroll
        for (int c = 0; c < CC; ++c)
            atomicAdd(&pooled[(size_t)g * CC + c], v[c]);
    }
}

// ---------------- final MLP ----------------
__global__ __launch_bounds__(256) void k_mlp(const float* __restrict__ pooled,
    const float* __restrict__ w1, const float* __restrict__ b1,
    const float* __restrict__ w2, const float* __restrict__ b2,
    const float* __restrict__ w3, const float* __restrict__ b3,
    float* __restrict__ out)
{
    int gi = blockIdx.x * 256 + threadIdx.x;
    if (gi >= GG) return;

    float p[CC];
    const float4* pp = reinterpret_cast<const float4*>(pooled + (size_t)gi * CC);
#pragma unroll
    for (int q = 0; q < 5; ++q) {
        float4 t = pp[q];
        p[4*q+0] = t.x; p[4*q+1] = t.y; p[4*q+2] = t.z; p[4*q+3] = t.w;
    }
    float h1[32];
#pragma unroll
    for (int j = 0; j < 32; ++j) h1[j] = b1[j];
#pragma unroll
    for (int c = 0; c < CC; ++c) {
        float pc = p[c];
#pragma unroll
        for (int j = 0; j < 32; ++j) h1[j] = fmaf(pc, w1[c*32 + j], h1[j]);
    }
#pragma unroll
    for (int j = 0; j < 32; ++j) h1[j] = tanhf(h1[j]);
    float h2[8];
#pragma unroll
    for (int j = 0; j < 8; ++j) h2[j] = b2[j];
#pragma unroll
    for (int c = 0; c < 32; ++c) {
        float hc = h1[c];
#pragma unroll
        for (int j = 0; j < 8; ++j) h2[j] = fmaf(hc, w2[c*8 + j], h2[j]);
    }
    float o = b3[0];
#pragma unroll
    for (int j = 0; j < 8; ++j) o = fmaf(tanhf(h2[j]), w3[j], o);
    out[gi] = o;
}

extern "C" void kernel_launch(void* const* d_in, const int* in_sizes, int n_in,
                              void* d_out, int out_size, void* d_ws, size_t ws_size,
                              hipStream_t stream) {
    const float* x   = (const float*)d_in[0];
    const int*   ei  = (const int*)d_in[1];
    const float* ea  = (const float*)d_in[2];
    const int*   bat = (const int*)d_in[3];
    const float* lfw = (const float*)d_in[4];
    const float* lfb = (const float*)d_in[5];
    const float* lsw = (const float*)d_in[6];
    const float* lsb = (const float*)d_in[7];
    const float* bng = (const float*)d_in[8];
    const float* bnb = (const float*)d_in[9];
    const float* w1  = (const float*)d_in[10];
    const float* b1  = (const float*)d_in[11];
    const float* w2  = (const float*)d_in[12];
    const float* b2  = (const float*)d_in[13];
    const float* w3  = (const float*)d_in[14];
    const float* b3  = (const float*)d_in[15];
    float* out = (float*)d_out;

    char* ws = (char*)d_ws;
    float* y      = (float*)ws;                        // NN*CC f      (8 MB)
    float* P0     = y + (size_t)NN * CC;               // NN*2CC f     (16 MB)
    float* PX     = P0 + (size_t)NN * 2 * CC;          // NN*2CC f     (16 MB)
    float* rec    = PX + (size_t)NN * 2 * CC;          // EE*16 f      (102.4 MB)
    int*   offs   = (int*)(rec + (size_t)EE * RSTRIDE);// NPAD
    int*   cur2   = offs + NPAD;                       // NPAD (written by scan_bc)
    int*   bsum   = cur2 + NPAD;                       // 256
    // zeroed region starts here:
    int*   cnt    = bsum + 256;                        // NN
    float* sums   = (float*)(cnt + NN);                // 2 layers * 2*CC
    float* pooled = sums + 2 * 2 * CC;                 // GG*CC

    size_t zbytes = ((size_t)NN + 2*2*CC + (size_t)GG*CC) * sizeof(int);
    hipMemsetAsync(cnt, 0, zbytes, stream);

    // ---- CSR build + record scatter (reused by both layers) ----
    k_hist<<<(EE/4 + 255) / 256, 256, 0, stream>>>(ei, cnt);
    k_scan_a<<<NB, SCAN_TPB, 0, stream>>>(cnt, offs, bsum);
    k_scan_bc<<<NPAD / 256, 256, 0, stream>>>(offs, bsum, cur2);
    k_rec<<<(EE + 255) / 256, 256, 0, stream>>>(ei, ea, cur2, rec);

    const int nblocks = (NN + 255) / 256;
    const int mblocks = (EE / 4 + 255) / 256;   // 1563

    // layer 0
    k_pre0<<<nblocks, 256, 0, stream>>>(x, lfw, lfb, lsw, lsb, P0, PX, y);
    k_msg<<<mblocks, 256, 0, stream>>>(rec, offs, P0, PX,
                                       lfw + 2*CC*CC, lsw + 2*CC*CC, y);
    k_bnstats<<<STAT_BLOCKS, 256, 0, stream>>>(y, sums);
    // BN(l0)+tanh in place, precompute P0/PX for layer 1
    k_bnpre<<<nblocks, 256, 0, stream>>>(y, sums, bng, bnb,
        lfw + (size_t)KK*CC, lfb + CC, lsw + (size_t)KK*CC, lsb + CC, P0, PX);
    // layer 1
    k_msg<<<mblocks, 256, 0, stream>>>(rec, offs, P0, PX,
        lfw + (size_t)KK*CC + 2*CC*CC, lsw + (size_t)KK*CC + 2*CC*CC, y);
    k_bnstats<<<STAT_BLOCKS, 256, 0, stream>>>(y, sums + 2*CC);
    // BN(l1)+tanh+pool
    k_bnpool<<<nblocks, 256, 0, stream>>>(y, sums + 2*CC, bng + CC, bnb + CC,
                                          bat, pooled);
    k_mlp<<<(GG + 255) / 256, 256, 0, stream>>>(pooled, w1, b1, w2, b2, w3, b3, out);
}